// Round 7
// baseline (8395.072 us; speedup 1.0000x reference)
//
#include <hip/hip_runtime.h>
#include <math.h>

typedef unsigned short u16;
typedef __attribute__((ext_vector_type(8))) short bf16x8;
typedef __attribute__((ext_vector_type(4))) float f32x4;

// ---- problem dims ----
static constexpr int D_S = 8192;
static constexpr int D_L = 4;
static constexpr int TOK = 65536;
static constexpr float NORMALIZER = 0.4204482076268573f;  // 32^-0.25
static constexpr float RATIO = 0.125f;                    // 64^-0.5
static constexpr float KEPS = 1e-4f;

// ---- workspace layout (float slots) ----
static constexpr size_t OFF_H     = 0;            // 16,777,216 fp32 residual
static constexpr size_t OFF_XNB   = 16777216;     // 8,388,608  bf16 xn [65536][256]
static constexpr size_t OFF_BIG   = 25165824;     // 16,777,216 bf16 k|q [65536][512] | FFN mid | xbf
static constexpr size_t OFF_V     = 41943040;     // 4,194,304  bf16 v/ao per-half [32768][256]
static constexpr size_t OFF_WKT   = 46399488;     // 131,072 combined [512][512] (WKt|WQt); also embWt
static constexpr size_t OFF_WVT   = 46530560;     // 65,536
static constexpr size_t OFF_WOT   = 46596096;     // 65,536
static constexpr size_t OFF_W1    = 46661632;     // 262,144
static constexpr size_t OFF_W2    = 46923776;     // 262,144
static constexpr size_t OFF_DG    = 47185920;     // 524,288 (bf16 [65536][16]: k-heads 0-7, q-heads 8-15)
static constexpr size_t OFF_KMAX  = 47710208;     // 64
static constexpr size_t OFF_PART  = 47710272;     // 2,097,152 (64bh x 16chunk x 2048)
static constexpr size_t OFF_PARTK = 49807424;     // 65,536
static constexpr size_t OFF_CTX   = 49872960;     // 131,072
static constexpr size_t OFF_KSUM  = 50004032;     // 4,096
static constexpr size_t OFF_POOL  = 50008128;     // 2,048
static constexpr size_t NEED_BYTES = 200040704;   // proven OK (round 5/6)

static __device__ __forceinline__ float bf2f(u16 u) {
  return __uint_as_float(((unsigned int)u) << 16);
}
static __device__ __forceinline__ u16 f2bf(float f) {
  unsigned int u = __float_as_uint(f);
  u = (u + 0x7fffu + ((u >> 16) & 1u)) >> 16;
  return (u16)u;
}
static __device__ __forceinline__ float geluf(float v) {
  return 0.5f * v * (1.f + erff(v * 0.70710678118654752f));
}
static __device__ __forceinline__ float dec_max(unsigned int mk) {
  return __uint_as_float((mk & 0x80000000u) ? (mk & 0x7fffffffu) : ~mk);
}

__global__ void report_kernel(float* out, float v) {
  if (threadIdx.x < 16) out[threadIdx.x] = v;
}

__global__ __launch_bounds__(256) void zero_kernel(float* p, int n) {
  int i = blockIdx.x * 256 + threadIdx.x;
  if (i < n) p[i] = 0.f;
}

// ================= x -> bf16 =================
__global__ __launch_bounds__(256) void xcvt_kernel(const float* __restrict__ x,
                                                   u16* __restrict__ xb) {
  int i4 = (blockIdx.x * 256 + threadIdx.x) * 4;
  float4 v = *(const float4*)(x + i4);
  u16 o[4] = {f2bf(v.x), f2bf(v.y), f2bf(v.z), f2bf(v.w)};
  *(uint2*)(xb + i4) = *(uint2*)o;
}

// ================= layernorm: fp32 in, bf16 out =================
__global__ __launch_bounds__(256) void ln_kernel(
    const float* __restrict__ src, u16* __restrict__ dst,
    const float* __restrict__ g, const float* __restrict__ b) {
  int wv = threadIdx.x >> 6, lane = threadIdx.x & 63;
  int t = blockIdx.x * 4 + wv;
  const float4 v = *(const float4*)(src + (size_t)t * 256 + lane * 4);
  float s1 = v.x + v.y + v.z + v.w;
  float s2 = v.x * v.x + v.y * v.y + v.z * v.z + v.w * v.w;
  for (int off = 32; off; off >>= 1) {
    s1 += __shfl_xor(s1, off);
    s2 += __shfl_xor(s2, off);
  }
  float mu = s1 * (1.f / 256.f);
  float var = s2 * (1.f / 256.f) - mu * mu;
  float rs = rsqrtf(var + 1e-5f);
  float4 gg = *(const float4*)(g + lane * 4);
  float4 bb = *(const float4*)(b + lane * 4);
  u16 o0 = f2bf((v.x - mu) * rs * gg.x + bb.x);
  u16 o1 = f2bf((v.y - mu) * rs * gg.y + bb.y);
  u16 o2 = f2bf((v.z - mu) * rs * gg.z + bb.z);
  u16 o3 = f2bf((v.w - mu) * rs * gg.w + bb.w);
  uint2 pk;
  pk.x = (unsigned)o0 | ((unsigned)o1 << 16);
  pk.y = (unsigned)o2 | ((unsigned)o3 << 16);
  *(uint2*)(dst + (size_t)t * 256 + lane * 4) = pk;
}

// ===== weight split: fp32 W[K][N] -> bf16 Wt[N][2K] (hi plane, lo plane) =====
__global__ __launch_bounds__(256) void wsplit_kernel(
    const float* __restrict__ W, u16* __restrict__ Wt, int K, int N, int nb) {
  int i = blockIdx.x * 256 + threadIdx.x;
  int k = i >> nb, n = i & (N - 1);
  float val = W[i];
  u16 hi = f2bf(val);
  u16 lo = f2bf(val - bf2f(hi));
  Wt[(size_t)n * 2 * K + k] = hi;
  Wt[(size_t)n * 2 * K + K + k] = lo;
}

// ===== paired split for two 256x256 weights =====
__global__ __launch_bounds__(256) void wsplit2_kernel(
    const float* __restrict__ Wa, const float* __restrict__ Wb,
    u16* __restrict__ Ta, u16* __restrict__ Tb) {
  int i = blockIdx.x * 256 + threadIdx.x;   // 0..131071
  const float* W = (i < 65536) ? Wa : Wb;
  u16* T = (i < 65536) ? Ta : Tb;
  int j = i & 65535;
  int k = j >> 8, n = j & 255;
  float val = W[j];
  u16 hi = f2bf(val);
  u16 lo = f2bf(val - bf2f(hi));
  T[(size_t)n * 512 + k] = hi;
  T[(size_t)n * 512 + 256 + k] = lo;
}

// ================= MFMA GEMM: 128x128 tile, A bf16 [M][K], Wt bf16 [N][2K] =================
// EPI: 0 plain (ACT gelu, ACC fp32-acc, OBF bf16 store)
//      4 embed (bias + pos, fp32 store, N=256)
//      5 kq (store bf16 + per-head diag)
template <int EPI, int ACT, int ACC, int OBF>
__global__ __launch_bounds__(256) void mfma_gemm(
    const u16* __restrict__ A, const u16* __restrict__ Wt,
    const float* __restrict__ bias, const float* __restrict__ posP,
    float* __restrict__ outF, u16* __restrict__ outB,
    u16* __restrict__ diagOut, int N, int K) {
  __shared__ __align__(16) u16 Als[4096];   // [q][row][8]
  __shared__ __align__(16) u16 Bls[4096];   // [q][col][8]
  const int K2 = K * 2;
  int tid = threadIdx.x;
  int bm = blockIdx.x * 128, bn = blockIdx.y * 128;
  int w = tid >> 6, lane = tid & 63;
  int wm = w >> 1, wn = w & 1;
  int lr = lane & 15, lq = lane >> 4;
  f32x4 acc[4][4];
#pragma unroll
  for (int i = 0; i < 4; ++i)
#pragma unroll
    for (int j = 0; j < 4; ++j) acc[i][j] = (f32x4){0.f, 0.f, 0.f, 0.f};
  int r0 = tid >> 2, q0 = tid & 3;
  for (int k0 = 0; k0 < K2; k0 += 32) {
    int kk = k0 + q0 * 8;
    int gka = kk & (K - 1);
    uint4 a0 = *(const uint4*)(A + (size_t)(bm + r0) * K + gka);
    uint4 a1 = *(const uint4*)(A + (size_t)(bm + r0 + 64) * K + gka);
    uint4 b0 = *(const uint4*)(Wt + (size_t)(bn + r0) * K2 + kk);
    uint4 b1 = *(const uint4*)(Wt + (size_t)(bn + r0 + 64) * K2 + kk);
    __syncthreads();
    ((uint4*)Als)[q0 * 128 + r0] = a0;
    ((uint4*)Als)[q0 * 128 + r0 + 64] = a1;
    ((uint4*)Bls)[q0 * 128 + r0] = b0;
    ((uint4*)Bls)[q0 * 128 + r0 + 64] = b1;
    __syncthreads();
    bf16x8 af[4], bfr[4];
#pragma unroll
    for (int mi = 0; mi < 4; ++mi)
      af[mi] = ((const bf16x8*)Als)[lq * 128 + wm * 64 + mi * 16 + lr];
#pragma unroll
    for (int ni = 0; ni < 4; ++ni)
      bfr[ni] = ((const bf16x8*)Bls)[lq * 128 + wn * 64 + ni * 16 + lr];
#pragma unroll
    for (int mi = 0; mi < 4; ++mi)
#pragma unroll
      for (int ni = 0; ni < 4; ++ni)
        acc[mi][ni] = __builtin_amdgcn_mfma_f32_16x16x32_bf16(af[mi], bfr[ni], acc[mi][ni], 0, 0, 0);
  }
  // ---- epilogues ----  C/D: col = lane&15, row = (lane>>4)*4 + r  [m89-verified]
  if (EPI == 0) {
#pragma unroll
    for (int ni = 0; ni < 4; ++ni) {
      int col = bn + wn * 64 + ni * 16 + lr;
      float bv = bias ? bias[col] : 0.f;
#pragma unroll
      for (int mi = 0; mi < 4; ++mi)
#pragma unroll
        for (int r = 0; r < 4; ++r) {
          int rowg = bm + wm * 64 + mi * 16 + lq * 4 + r;
          float val = acc[mi][ni][r] + bv;
          if (ACT) val = geluf(val);
          size_t o = (size_t)rowg * N + col;
          if (OBF) outB[o] = f2bf(val);
          else if (ACC) outF[o] += val;
          else outF[o] = val;
        }
    }
  }
  if (EPI == 4) {  // embed: + bias + pos, fp32 store (N==256)
#pragma unroll
    for (int ni = 0; ni < 4; ++ni) {
      int col = bn + wn * 64 + ni * 16 + lr;
      float bv = bias[col];
#pragma unroll
      for (int mi = 0; mi < 4; ++mi)
#pragma unroll
        for (int r = 0; r < 4; ++r) {
          int rowg = bm + wm * 64 + mi * 16 + lq * 4 + r;
          outF[(size_t)rowg * 256 + col] =
              acc[mi][ni][r] + bv + posP[(size_t)(rowg & (D_S - 1)) * 256 + col];
        }
    }
  }
  if (EPI == 5) {  // kq: store raw bf16 + per-head diag (32-col heads); dg [t][16]
#pragma unroll
    for (int ni = 0; ni < 4; ++ni) {
      int col = bn + wn * 64 + ni * 16 + lr;
#pragma unroll
      for (int mi = 0; mi < 4; ++mi)
#pragma unroll
        for (int r = 0; r < 4; ++r) {
          int rowg = bm + wm * 64 + mi * 16 + lq * 4 + r;
          outB[(size_t)rowg * N + col] = f2bf(acc[mi][ni][r]);
        }
    }
    const float c05n2 = 0.5f * NORMALIZER * NORMALIZER;
    int hb = (bn + wn * 64) >> 5;
#pragma unroll
    for (int mi = 0; mi < 4; ++mi) {
      float s0[4] = {0.f, 0.f, 0.f, 0.f}, s1[4] = {0.f, 0.f, 0.f, 0.f};
#pragma unroll
      for (int ni = 0; ni < 4; ++ni)
#pragma unroll
        for (int r = 0; r < 4; ++r) {
          float v = acc[mi][ni][r];
          if (ni < 2) s0[r] += v * v; else s1[r] += v * v;
        }
#pragma unroll
      for (int r = 0; r < 4; ++r) {
        float a = s0[r], b = s1[r];
        a += __shfl_xor(a, 1); a += __shfl_xor(a, 2); a += __shfl_xor(a, 4); a += __shfl_xor(a, 8);
        b += __shfl_xor(b, 1); b += __shfl_xor(b, 2); b += __shfl_xor(b, 4); b += __shfl_xor(b, 8);
        if (lr == 0) {
          int rowg = bm + wm * 64 + mi * 16 + lq * 4 + r;
          diagOut[(size_t)rowg * 16 + hb] = f2bf(c05n2 * a);
          diagOut[(size_t)rowg * 16 + hb + 1] = f2bf(c05n2 * b);
        }
      }
    }
  }
}

// ===== kpmax: global max of xp = (k*norm)@projT per (b,head) =====
__global__ __launch_bounds__(256) void kpmax_kernel(
    const u16* __restrict__ kq, const float* __restrict__ proj,
    unsigned int* __restrict__ kmaxk) {
  __shared__ float projS[64 * 33];
  __shared__ float kS[64 * 33];
  __shared__ float red[4];
  int tid = threadIdx.x;
  int bh = blockIdx.x, chunk = blockIdx.y;
  int b = bh >> 3, head = bh & 7;
  int t0 = b * 8192 + chunk * 1024;
#pragma unroll
  for (int u = 0; u < 8; ++u) {
    int i = tid + u * 256;
    projS[(i >> 5) * 33 + (i & 31)] = proj[i];
  }
  int m = tid & 63, sub = tid >> 6;
  float mx = -3.4e38f;
  int row = tid >> 2, c0 = (tid & 3) * 8;
  for (int tile = 0; tile < 16; ++tile) {
    int nb = tile * 64;
    __syncthreads();
    {
      u16 tmp[8];
      *(uint4*)tmp = *(const uint4*)(kq + (size_t)(t0 + nb + row) * 512 + head * 32 + c0);
#pragma unroll
      for (int j = 0; j < 8; ++j) kS[row * 33 + c0 + j] = bf2f(tmp[j]) * NORMALIZER;
    }
    __syncthreads();
#pragma unroll
    for (int i = 0; i < 16; ++i) {
      int n = sub * 16 + i;
      float xp = 0.f;
#pragma unroll
      for (int d = 0; d < 32; ++d) xp += kS[n * 33 + d] * projS[m * 33 + d];
      mx = fmaxf(mx, xp);
    }
  }
#pragma unroll
  for (int off = 1; off < 64; off <<= 1) mx = fmaxf(mx, __shfl_xor(mx, off));
  if ((tid & 63) == 0) red[tid >> 6] = mx;
  __syncthreads();
  if (tid == 0) {
    float t = fmaxf(fmaxf(red[0], red[1]), fmaxf(red[2], red[3]));
    unsigned int u = __float_as_uint(t);
    unsigned int key = (u & 0x80000000u) ? ~u : (u | 0x80000000u);
    atomicMax(kmaxk + bh, key);
  }
}

// ===== ctxaccum: inline kp = ratio*(exp((k*norm)@projT - dg - mx)+eps); part += kp^T @ v =====
__global__ __launch_bounds__(256) void ctxaccum_kernel(
    const u16* __restrict__ kq, const u16* __restrict__ v,
    const float* __restrict__ proj, const u16* __restrict__ dg,
    const unsigned int* __restrict__ kmaxk,
    float* __restrict__ part, float* __restrict__ partk, int hf) {
  __shared__ float projS[64 * 33];
  __shared__ float kS[64 * 33];
  __shared__ float vS[64 * 32];
  __shared__ float kpS[64 * 64];
  __shared__ float dgS[64];
  int tid = threadIdx.x;
  int bl = blockIdx.x >> 3, head = blockIdx.x & 7, c = blockIdx.y;
  int n0l = bl * 8192 + c * 512;     // within half
  int b = hf * 4 + bl;
  int bhg = b * 8 + head;
  int tg0 = hf * 32768 + n0l;        // global token base
#pragma unroll
  for (int u = 0; u < 8; ++u) {
    int i = tid + u * 256;
    projS[(i >> 5) * 33 + (i & 31)] = proj[i];
  }
  float mx = dec_max(kmaxk[bhg]);
  int m = tid & 63, sub = tid >> 6;
  int row = tid >> 2, c0 = (tid & 3) * 8;
  float acc[8] = {};
  float ks = 0.f;
  for (int tile = 0; tile < 8; ++tile) {
    int nb = tile * 64;
    __syncthreads();
    {
      u16 tmp[8];
      *(uint4*)tmp = *(const uint4*)(kq + (size_t)(tg0 + nb + row) * 512 + head * 32 + c0);
#pragma unroll
      for (int j = 0; j < 8; ++j) kS[row * 33 + c0 + j] = bf2f(tmp[j]) * NORMALIZER;
      *(uint4*)tmp = *(const uint4*)(v + (size_t)(n0l + nb + row) * 256 + head * 32 + c0);
#pragma unroll
      for (int j = 0; j < 8; ++j) vS[row * 32 + c0 + j] = bf2f(tmp[j]);
    }
    if (tid < 64) dgS[tid] = bf2f(dg[(size_t)(tg0 + nb + tid) * 16 + head]);
    __syncthreads();
#pragma unroll
    for (int i = 0; i < 16; ++i) {
      int n = sub * 16 + i;
      float xp = 0.f;
#pragma unroll
      for (int d = 0; d < 32; ++d) xp += kS[n * 33 + d] * projS[m * 33 + d];
      kpS[n * 64 + m] = RATIO * (__expf(xp - dgS[n] - mx) + KEPS);
    }
    __syncthreads();
#pragma unroll 4
    for (int n = 0; n < 64; ++n) {
      float kv = kpS[n * 64 + m];
      if (sub == 0) ks += kv;
      const float* vr = &vS[n * 32 + sub * 8];
#pragma unroll
      for (int j = 0; j < 8; ++j) acc[j] += kv * vr[j];
    }
  }
  float* pp = part + ((size_t)bhg * 16 + c) * 2048 + m * 32 + sub * 8;
#pragma unroll
  for (int j = 0; j < 8; ++j) pp[j] = acc[j];
  if (sub == 0) partk[((size_t)bhg * 16 + c) * 64 + m] = ks;
}

__global__ __launch_bounds__(256) void ctxreduce_kernel(
    const float* __restrict__ part, const float* __restrict__ partk,
    float* __restrict__ ctx, float* __restrict__ ksum) {
  int bh = blockIdx.x, tid = threadIdx.x;
#pragma unroll
  for (int i = 0; i < 8; ++i) {
    int idx = tid + i * 256;
    float s = 0.f;
#pragma unroll
    for (int cc = 0; cc < 16; ++cc)
      s += part[((size_t)bh * 16 + cc) * 2048 + idx];
    ctx[(size_t)bh * 2048 + idx] = s;
  }
  if (tid < 64) {
    float s = 0.f;
#pragma unroll
    for (int cc = 0; cc < 16; ++cc) s += partk[((size_t)bh * 16 + cc) * 64 + tid];
    ksum[bh * 64 + tid] = s;
  }
}

// ===== attnout: inline qp (row-max + exp) from q; ao = (qp@ctx)/(qp@ksum) =====
__global__ __launch_bounds__(256) void attnout_kernel(
    const u16* __restrict__ kq, const float* __restrict__ proj,
    const u16* __restrict__ dg, const float* __restrict__ ctx,
    const float* __restrict__ ksum, u16* __restrict__ ao, int hf) {
  __shared__ float ctxS[2048];
  __shared__ float ksS[64];
  __shared__ float projS[64 * 33];
  __shared__ float qS[64 * 33];
  __shared__ float xpS[64 * 65];
  __shared__ float dgS[64];
  __shared__ float rmS[64];
  int tid = threadIdx.x;
  int rb = blockIdx.x, head = blockIdx.y;
  int n0l = rb * 64;
  int t0g = hf * 32768 + n0l;
  int bhg = (t0g >> 13) * 8 + head;
#pragma unroll
  for (int i = 0; i < 8; ++i) {
    int idx = tid + i * 256;
    ctxS[idx] = ctx[(size_t)bhg * 2048 + idx];
    projS[(idx >> 5) * 33 + (idx & 31)] = proj[idx];
  }
  if (tid < 64) {
    ksS[tid] = ksum[bhg * 64 + tid];
    dgS[tid] = bf2f(dg[(size_t)(t0g + tid) * 16 + 8 + head]);
  }
  {
    int row = tid >> 2, c0 = (tid & 3) * 8;
    u16 tmp[8];
    *(uint4*)tmp = *(const uint4*)(kq + (size_t)(t0g + row) * 512 + 256 + head * 32 + c0);
#pragma unroll
    for (int j = 0; j < 8; ++j) qS[row * 33 + c0 + j] = bf2f(tmp[j]) * NORMALIZER;
  }
  __syncthreads();
  int m = tid & 63, sub = tid >> 6;
#pragma unroll
  for (int i = 0; i < 16; ++i) {
    int t = sub * 16 + i;
    float xp = 0.f;
#pragma unroll
    for (int d = 0; d < 32; ++d) xp += qS[t * 33 + d] * projS[m * 33 + d];
    xpS[t * 65 + m] = xp;
  }
  __syncthreads();
  if (tid < 64) {
    float rm = -3.4e38f;
#pragma unroll
    for (int j = 0; j < 64; ++j) rm = fmaxf(rm, xpS[tid * 65 + j]);
    rmS[tid] = rm;
  }
  __syncthreads();
#pragma unroll
  for (int i = 0; i < 16; ++i) {
    int t = sub * 16 + i;
    xpS[t * 65 + m] = RATIO * (__expf(xpS[t * 65 + m] - dgS[t] - rmS[t]) + KEPS);
  }
  __syncthreads();
  {
    int e = tid & 31, tg = tid >> 5;
#pragma unroll
    for (int it = 0; it < 8; ++it) {
      int t = it * 8 + tg;
      float num = 0.f, den = 0.f;
#pragma unroll
      for (int mm = 0; mm < 64; ++mm) {
        float qv = xpS[t * 65 + mm];
        num += qv * ctxS[mm * 32 + e];
        den += qv * ksS[mm];
      }
      ao[(size_t)(n0l + t) * 256 + head * 32 + e] = f2bf(num / den);
    }
  }
}

// ================= mean pool + final FC (fp32 h) =================
__global__ __launch_bounds__(256) void pool_kernel(
    const float* __restrict__ h, float* __restrict__ pooled) {
  int b = blockIdx.x, chunk = blockIdx.y, j = threadIdx.x;
  const float* hp = h + (size_t)(b * D_S + chunk * 256) * 256 + j;
  float acc = 0.f;
#pragma unroll 4
  for (int s = 0; s < 256; ++s) acc += hp[(size_t)s * 256];
  atomicAdd(pooled + b * 256 + j, acc);
}

__global__ __launch_bounds__(64) void final_kernel(
    const float* __restrict__ pooled, const float* __restrict__ fcw,
    const float* __restrict__ fcb, float* __restrict__ out) {
  int tid = threadIdx.x;
  if (tid >= 16) return;
  int b = tid >> 1, c = tid & 1;
  float acc = 0.f;
  for (int j = 0; j < 256; ++j) acc += pooled[b * 256 + j] * fcw[j * 2 + c];
  out[b * 2 + c] = acc * (1.f / 8192.f) + fcb[c];
}

extern "C" void kernel_launch(void* const* d_in, const int* in_sizes, int n_in,
                              void* d_out, int out_size, void* d_ws, size_t ws_size,
                              hipStream_t stream) {
  const float* x     = (const float*)d_in[0];
  const float* emb_w = (const float*)d_in[1];
  const float* emb_b = (const float*)d_in[2];
  const float* pos   = (const float*)d_in[3];
  const float* ln1_g = (const float*)d_in[4];
  const float* ln1_b = (const float*)d_in[5];
  const float* wq    = (const float*)d_in[6];
  const float* wk    = (const float*)d_in[7];
  const float* wv    = (const float*)d_in[8];
  const float* wo    = (const float*)d_in[9];
  const float* bo    = (const float*)d_in[10];
  const float* ln2_g = (const float*)d_in[11];
  const float* ln2_b = (const float*)d_in[12];
  const float* w1    = (const float*)d_in[13];
  const float* b1    = (const float*)d_in[14];
  const float* w2    = (const float*)d_in[15];
  const float* b2    = (const float*)d_in[16];
  const float* proj  = (const float*)d_in[17];
  const float* fc_w  = (const float*)d_in[18];
  const float* fc_b  = (const float*)d_in[19];

  if (ws_size < NEED_BYTES) {
    report_kernel<<<1, 64, 0, stream>>>((float*)d_out, (float)ws_size);
    return;
  }

  float* ws = (float*)d_ws;
  float* h      = ws + OFF_H;
  u16* xnb      = (u16*)(ws + OFF_XNB);
  u16* BIG      = (u16*)(ws + OFF_BIG);
  u16* Vb       = (u16*)(ws + OFF_V);
  u16* WKQt     = (u16*)(ws + OFF_WKT);   // combined [512][512]; also embWt pre-layers
  u16* WQt      = WKQt + 262144 / 2;      // rows 256..511 (offset 256*512 u16)
  u16* WVt      = (u16*)(ws + OFF_WVT);
  u16* WOt      = (u16*)(ws + OFF_WOT);
  u16* W1t      = (u16*)(ws + OFF_W1);
  u16* W2t      = (u16*)(ws + OFF_W2);
  u16* dg       = (u16*)(ws + OFF_DG);
  unsigned int* kmaxk = (unsigned int*)(ws + OFF_KMAX);
  float* part   = ws + OFF_PART;
  float* partk  = ws + OFF_PARTK;
  float* ctx    = ws + OFF_CTX;
  float* ksum   = ws + OFF_KSUM;
  float* pooled = ws + OFF_POOL;

  // ---- embed as MFMA GEMM: xbf(=BIG) [65536][64] @ embWt(=WKQt) [256][128] ----
  xcvt_kernel<<<4096, 256, 0, stream>>>(x, BIG);
  wsplit_kernel<<<64, 256, 0, stream>>>(emb_w, WKQt, 64, 256, 8);
  mfma_gemm<4, 0, 0, 0><<<dim3(512, 2), 256, 0, stream>>>(
      BIG, WKQt, emb_b, pos, h, nullptr, nullptr, 256, 64);

  for (int l = 0; l < D_L; ++l) {
    const float* pj = proj + l * 2048;
    ln_kernel<<<TOK / 4, 256, 0, stream>>>(h, xnb, ln1_g + l * 256, ln1_b + l * 256);
    wsplit2_kernel<<<512, 256, 0, stream>>>(wk + l * 65536, wq + l * 65536, WKQt, WQt);
    wsplit2_kernel<<<512, 256, 0, stream>>>(wv + l * 65536, wo + l * 65536, WVt, WOt);
    wsplit_kernel<<<1024, 256, 0, stream>>>(w1 + l * 262144, W1t, 256, 1024, 10);
    wsplit_kernel<<<1024, 256, 0, stream>>>(w2 + l * 262144, W2t, 1024, 256, 8);
    zero_kernel<<<1, 256, 0, stream>>>((float*)kmaxk, 64);

    // k|q = xn @ [wk|wq], fused raw-store + per-head diag
    mfma_gemm<5, 0, 0, 1><<<dim3(512, 4), 256, 0, stream>>>(
        xnb, WKQt, nullptr, nullptr, nullptr, BIG, dg, 512, 256);
    // global max of k-projection per (b, head)
    kpmax_kernel<<<dim3(64, 8), 256, 0, stream>>>(BIG, pj, kmaxk);
    // context accumulation per half (kp computed inline)
    for (int hf = 0; hf < 2; ++hf) {
      const u16* xh = xnb + (size_t)hf * 32768 * 256;
      mfma_gemm<0, 0, 0, 1><<<dim3(256, 2), 256, 0, stream>>>(
          xh, WVt, nullptr, nullptr, nullptr, Vb, nullptr, 256, 256);
      ctxaccum_kernel<<<dim3(32, 16), 256, 0, stream>>>(
          BIG, Vb, pj, dg, kmaxk, part, partk, hf);
    }
    ctxreduce_kernel<<<64, 256, 0, stream>>>(part, partk, ctx, ksum);
    // attention out per half (qp computed inline), then Wo
    for (int hf = 0; hf < 2; ++hf) {
      float* hh = h + (size_t)hf * 32768 * 256;
      attnout_kernel<<<dim3(512, 8), 256, 0, stream>>>(BIG, pj, dg, ctx, ksum, Vb, hf);
      mfma_gemm<0, 0, 1, 0><<<dim3(256, 2), 256, 0, stream>>>(
          Vb, WOt, bo + l * 256, nullptr, hh, nullptr, nullptr, 256, 256);
    }

    ln_kernel<<<TOK / 4, 256, 0, stream>>>(h, xnb, ln2_g + l * 256, ln2_b + l * 256);
    for (int hf = 0; hf < 2; ++hf) {
      const u16* xh = xnb + (size_t)hf * 32768 * 256;
      float* hh = h + (size_t)hf * 32768 * 256;
      mfma_gemm<0, 1, 0, 1><<<dim3(256, 8), 256, 0, stream>>>(
          xh, W1t, b1 + l * 1024, nullptr, nullptr, BIG, nullptr, 1024, 256);
      mfma_gemm<0, 0, 1, 0><<<dim3(256, 2), 256, 0, stream>>>(
          BIG, W2t, b2 + l * 256, nullptr, hh, nullptr, nullptr, 256, 1024);
    }
  }

  zero_kernel<<<8, 256, 0, stream>>>(pooled, 2048);
  pool_kernel<<<dim3(8, 32), 256, 0, stream>>>(h, pooled);
  final_kernel<<<1, 64, 0, stream>>>(pooled, fc_w, fc_b, (float*)d_out);
}

// Round 8
// 3987.995 us; speedup vs baseline: 2.1051x; 2.1051x over previous
//
#include <hip/hip_runtime.h>
#include <math.h>

typedef unsigned short u16;
typedef __attribute__((ext_vector_type(8))) short bf16x8;
typedef __attribute__((ext_vector_type(4))) float f32x4;

// ---- problem dims ----
static constexpr int D_S = 8192;
static constexpr int D_L = 4;
static constexpr int TOK = 65536;
static constexpr float NORMALIZER = 0.4204482076268573f;  // 32^-0.25
static constexpr float RATIO = 0.125f;                    // 64^-0.5
static constexpr float KEPS = 1e-4f;

// ---- workspace layout (float slots) ----  (round-5/6 proven layout)
static constexpr size_t OFF_H     = 0;            // 16,777,216 fp32 residual
static constexpr size_t OFF_XNB   = 16777216;     // 8,388,608  bf16 xn [65536][256]
static constexpr size_t OFF_BIG   = 25165824;     // 16,777,216 bf16 xp/kp/qp [65536][512] | FFN mid | xbf
static constexpr size_t OFF_V     = 41943040;     // 4,194,304  bf16 v/ao per-half [32768][256]
static constexpr size_t OFF_WKP   = 46137344;     // 131,072  (also embWt before the layer loop)
static constexpr size_t OFF_WQP   = 46268416;     // 131,072
static constexpr size_t OFF_WK    = 46399488;     // 65,536  (WQ follows contiguously -> combined [512][512])
static constexpr size_t OFF_WQ    = 46465024;     // 65,536
static constexpr size_t OFF_WV    = 46530560;     // 65,536
static constexpr size_t OFF_WO    = 46596096;     // 65,536
static constexpr size_t OFF_W1    = 46661632;     // 262,144
static constexpr size_t OFF_W2    = 46923776;     // 262,144
static constexpr size_t OFF_DG    = 47185920;     // 524,288 (bf16 [65536][16]: k-heads 0-7, q-heads 8-15)
static constexpr size_t OFF_KMAX  = 47710208;     // 64
static constexpr size_t OFF_PART  = 47710272;     // 2,097,152 (64bh x 16chunk x 2048)
static constexpr size_t OFF_PARTK = 49807424;     // 65,536
static constexpr size_t OFF_CTX   = 49872960;     // 131,072
static constexpr size_t OFF_KSUM  = 50004032;     // 4,096
static constexpr size_t OFF_POOL  = 50008128;     // 2,048
static constexpr size_t NEED_BYTES = 200040704;   // proven OK (rounds 5-7)

static __device__ __forceinline__ float bf2f(u16 u) {
  return __uint_as_float(((unsigned int)u) << 16);
}
static __device__ __forceinline__ u16 f2bf(float f) {
  unsigned int u = __float_as_uint(f);
  u = (u + 0x7fffu + ((u >> 16) & 1u)) >> 16;
  return (u16)u;
}
static __device__ __forceinline__ float geluf(float v) {
  return 0.5f * v * (1.f + erff(v * 0.70710678118654752f));
}

__global__ void report_kernel(float* out, float v) {
  if (threadIdx.x < 16) out[threadIdx.x] = v;
}

__global__ __launch_bounds__(256) void zero_kernel(float* p, int n) {
  int i = blockIdx.x * 256 + threadIdx.x;
  if (i < n) p[i] = 0.f;
}

// ================= x -> bf16 =================
__global__ __launch_bounds__(256) void xcvt_kernel(const float* __restrict__ x,
                                                   u16* __restrict__ xb) {
  int i4 = (blockIdx.x * 256 + threadIdx.x) * 4;
  float4 v = *(const float4*)(x + i4);
  u16 o[4] = {f2bf(v.x), f2bf(v.y), f2bf(v.z), f2bf(v.w)};
  *(uint2*)(xb + i4) = *(uint2*)o;
}

// ================= layernorm: fp32 in, bf16 out =================
__global__ __launch_bounds__(256) void ln_kernel(
    const float* __restrict__ src, u16* __restrict__ dst,
    const float* __restrict__ g, const float* __restrict__ b) {
  int wv = threadIdx.x >> 6, lane = threadIdx.x & 63;
  int t = blockIdx.x * 4 + wv;
  const float4 v = *(const float4*)(src + (size_t)t * 256 + lane * 4);
  float s1 = v.x + v.y + v.z + v.w;
  float s2 = v.x * v.x + v.y * v.y + v.z * v.z + v.w * v.w;
  for (int off = 32; off; off >>= 1) {
    s1 += __shfl_xor(s1, off);
    s2 += __shfl_xor(s2, off);
  }
  float mu = s1 * (1.f / 256.f);
  float var = s2 * (1.f / 256.f) - mu * mu;
  float rs = rsqrtf(var + 1e-5f);
  float4 gg = *(const float4*)(g + lane * 4);
  float4 bb = *(const float4*)(b + lane * 4);
  u16 o0 = f2bf((v.x - mu) * rs * gg.x + bb.x);
  u16 o1 = f2bf((v.y - mu) * rs * gg.y + bb.y);
  u16 o2 = f2bf((v.z - mu) * rs * gg.z + bb.z);
  u16 o3 = f2bf((v.w - mu) * rs * gg.w + bb.w);
  uint2 pk;
  pk.x = (unsigned)o0 | ((unsigned)o1 << 16);
  pk.y = (unsigned)o2 | ((unsigned)o3 << 16);
  *(uint2*)(dst + (size_t)t * 256 + lane * 4) = pk;
}

// ===== weight split: fp32 W[K][N] -> bf16 Wt[N][2K] (hi plane, lo plane) =====
__global__ __launch_bounds__(256) void wsplit_kernel(
    const float* __restrict__ W, u16* __restrict__ Wt, int K, int N, int nb) {
  int i = blockIdx.x * 256 + threadIdx.x;
  int k = i >> nb, n = i & (N - 1);
  float val = W[i];
  u16 hi = f2bf(val);
  u16 lo = f2bf(val - bf2f(hi));
  Wt[(size_t)n * 2 * K + k] = hi;
  Wt[(size_t)n * 2 * K + K + k] = lo;
}

// ===== paired split for two 256x256 weights =====
__global__ __launch_bounds__(256) void wsplit2_kernel(
    const float* __restrict__ Wa, const float* __restrict__ Wb,
    u16* __restrict__ Ta, u16* __restrict__ Tb) {
  int i = blockIdx.x * 256 + threadIdx.x;   // 0..131071
  const float* W = (i < 65536) ? Wa : Wb;
  u16* T = (i < 65536) ? Ta : Tb;
  int j = i & 65535;
  int k = j >> 8, n = j & 255;
  float val = W[j];
  u16 hi = f2bf(val);
  u16 lo = f2bf(val - bf2f(hi));
  T[(size_t)n * 512 + k] = hi;
  T[(size_t)n * 512 + 256 + k] = lo;
}

// ===== WKP/WQP build+split: Wt[n=h*64+m][2*256], val = norm * sum_d w[k][h*32+d]*proj[m][d] =====
__global__ __launch_bounds__(256) void wprojsplit_kernel(
    const float* __restrict__ w, const float* __restrict__ proj,
    u16* __restrict__ Wt) {
  int i = blockIdx.x * 256 + threadIdx.x;   // 131072
  int k = i & 255, n = i >> 8;
  int head = n >> 6, m = n & 63;
  float s = 0.f;
#pragma unroll
  for (int d = 0; d < 32; ++d) s += w[k * 256 + head * 32 + d] * proj[m * 32 + d];
  s *= NORMALIZER;
  u16 hi = f2bf(s);
  u16 lo = f2bf(s - bf2f(hi));
  Wt[(size_t)n * 512 + k] = hi;
  Wt[(size_t)n * 512 + 256 + k] = lo;
}

// ================= MFMA GEMM: 128x128 tile, A bf16 [M][K], Wt bf16 [N][2K] =================
// K-loop: round-4 form (no register carry across barriers — m141 lesson).
// EPI: 0 plain (ACT gelu, ACC fp32-acc, OBF bf16 store), 1 per-head diag,
//      2 xp-store+max, 3 qp, 4 embed (bias + pos, fp32 store, N=256)
template <int EPI, int ACT, int ACC, int OBF>
__global__ __launch_bounds__(256) void mfma_gemm(
    const u16* __restrict__ A, const u16* __restrict__ Wt,
    const float* __restrict__ bias, const float* __restrict__ posP,
    const u16* __restrict__ diagIn,
    float* __restrict__ outF, u16* __restrict__ outB,
    u16* __restrict__ diagOut, unsigned int* __restrict__ kmaxOut,
    int N, int K) {
  __shared__ __align__(16) u16 Als[4096];   // [q][row][8]
  __shared__ __align__(16) u16 Bls[4096];   // [q][col][8]
  const int K2 = K * 2;
  int tid = threadIdx.x;
  int bm = blockIdx.x * 128, bn = blockIdx.y * 128;
  int w = tid >> 6, lane = tid & 63;
  int wm = w >> 1, wn = w & 1;
  int lr = lane & 15, lq = lane >> 4;
  f32x4 acc[4][4];
#pragma unroll
  for (int i = 0; i < 4; ++i)
#pragma unroll
    for (int j = 0; j < 4; ++j) acc[i][j] = (f32x4){0.f, 0.f, 0.f, 0.f};
  int r0 = tid >> 2, q0 = tid & 3;
  for (int k0 = 0; k0 < K2; k0 += 32) {
    int kk = k0 + q0 * 8;
    int gka = kk & (K - 1);
    uint4 a0 = *(const uint4*)(A + (size_t)(bm + r0) * K + gka);
    uint4 a1 = *(const uint4*)(A + (size_t)(bm + r0 + 64) * K + gka);
    uint4 b0 = *(const uint4*)(Wt + (size_t)(bn + r0) * K2 + kk);
    uint4 b1 = *(const uint4*)(Wt + (size_t)(bn + r0 + 64) * K2 + kk);
    __syncthreads();
    ((uint4*)Als)[q0 * 128 + r0] = a0;
    ((uint4*)Als)[q0 * 128 + r0 + 64] = a1;
    ((uint4*)Bls)[q0 * 128 + r0] = b0;
    ((uint4*)Bls)[q0 * 128 + r0 + 64] = b1;
    __syncthreads();
    bf16x8 af[4], bfr[4];
#pragma unroll
    for (int mi = 0; mi < 4; ++mi)
      af[mi] = ((const bf16x8*)Als)[lq * 128 + wm * 64 + mi * 16 + lr];
#pragma unroll
    for (int ni = 0; ni < 4; ++ni)
      bfr[ni] = ((const bf16x8*)Bls)[lq * 128 + wn * 64 + ni * 16 + lr];
#pragma unroll
    for (int mi = 0; mi < 4; ++mi)
#pragma unroll
      for (int ni = 0; ni < 4; ++ni)
        acc[mi][ni] = __builtin_amdgcn_mfma_f32_16x16x32_bf16(af[mi], bfr[ni], acc[mi][ni], 0, 0, 0);
  }
  // ---- epilogues ----  C/D: col = lane&15, row = (lane>>4)*4 + r  [m89-verified]
  if (EPI == 0) {
#pragma unroll
    for (int ni = 0; ni < 4; ++ni) {
      int col = bn + wn * 64 + ni * 16 + lr;
      float bv = bias ? bias[col] : 0.f;
#pragma unroll
      for (int mi = 0; mi < 4; ++mi)
#pragma unroll
        for (int r = 0; r < 4; ++r) {
          int rowg = bm + wm * 64 + mi * 16 + lq * 4 + r;
          float val = acc[mi][ni][r] + bv;
          if (ACT) val = geluf(val);
          size_t o = (size_t)rowg * N + col;
          if (OBF) outB[o] = f2bf(val);
          else if (ACC) outF[o] += val;
          else outF[o] = val;
        }
    }
  }
  if (EPI == 1) {  // diag per head (32 cols); wave spans 2 heads; dg layout [t][16]
    const float c05n2 = 0.5f * NORMALIZER * NORMALIZER;
    int hb = (bn + wn * 64) >> 5;
#pragma unroll
    for (int mi = 0; mi < 4; ++mi) {
      float s0[4] = {0.f, 0.f, 0.f, 0.f}, s1[4] = {0.f, 0.f, 0.f, 0.f};
#pragma unroll
      for (int ni = 0; ni < 4; ++ni)
#pragma unroll
        for (int r = 0; r < 4; ++r) {
          float v = acc[mi][ni][r];
          if (ni < 2) s0[r] += v * v; else s1[r] += v * v;
        }
#pragma unroll
      for (int r = 0; r < 4; ++r) {
        float a = s0[r], b = s1[r];
        a += __shfl_xor(a, 1); a += __shfl_xor(a, 2); a += __shfl_xor(a, 4); a += __shfl_xor(a, 8);
        b += __shfl_xor(b, 1); b += __shfl_xor(b, 2); b += __shfl_xor(b, 4); b += __shfl_xor(b, 8);
        if (lr == 0) {
          int rowg = bm + wm * 64 + mi * 16 + lq * 4 + r;
          diagOut[(size_t)rowg * 16 + hb] = f2bf(c05n2 * a);
          diagOut[(size_t)rowg * 16 + hb + 1] = f2bf(c05n2 * b);
        }
      }
    }
  }
  if (EPI == 2) {  // store bf16 xp + global max per (b, head)
    float mx = -3.4e38f;
#pragma unroll
    for (int mi = 0; mi < 4; ++mi)
#pragma unroll
      for (int ni = 0; ni < 4; ++ni)
#pragma unroll
        for (int r = 0; r < 4; ++r) {
          float v = acc[mi][ni][r];
          mx = fmaxf(mx, v);
          int rowg = bm + wm * 64 + mi * 16 + lq * 4 + r;
          int col = bn + wn * 64 + ni * 16 + lr;
          outB[(size_t)rowg * N + col] = f2bf(v);
        }
#pragma unroll
    for (int off = 1; off < 64; off <<= 1) mx = fmaxf(mx, __shfl_xor(mx, off));
    if (lane == 0) {
      int b = bm >> 13;
      int head = (bn + wn * 64) >> 6;
      unsigned int u = __float_as_uint(mx);
      unsigned int key = (u & 0x80000000u) ? ~u : (u | 0x80000000u);
      atomicMax(kmaxOut + b * 8 + head, key);
    }
  }
  if (EPI == 3) {  // qp: in-wave row-max over the head's 64 cols, then exp; dg q-heads at +8
    int head = (bn + wn * 64) >> 6;
#pragma unroll
    for (int mi = 0; mi < 4; ++mi) {
      float rm[4] = {-3.4e38f, -3.4e38f, -3.4e38f, -3.4e38f};
#pragma unroll
      for (int ni = 0; ni < 4; ++ni)
#pragma unroll
        for (int r = 0; r < 4; ++r) rm[r] = fmaxf(rm[r], acc[mi][ni][r]);
#pragma unroll
      for (int r = 0; r < 4; ++r) {
        float t = rm[r];
        t = fmaxf(t, __shfl_xor(t, 1)); t = fmaxf(t, __shfl_xor(t, 2));
        t = fmaxf(t, __shfl_xor(t, 4)); t = fmaxf(t, __shfl_xor(t, 8));
        rm[r] = t;
      }
#pragma unroll
      for (int r = 0; r < 4; ++r) {
        int rowg = bm + wm * 64 + mi * 16 + lq * 4 + r;
        float dg = bf2f(diagIn[(size_t)rowg * 16 + 8 + head]);
#pragma unroll
        for (int ni = 0; ni < 4; ++ni) {
          int col = bn + wn * 64 + ni * 16 + lr;
          float v = RATIO * (__expf(acc[mi][ni][r] - dg - rm[r]) + KEPS);
          outB[(size_t)rowg * N + col] = f2bf(v);
        }
      }
    }
  }
  if (EPI == 4) {  // embed: + bias + pos, fp32 store (N==256)
#pragma unroll
    for (int ni = 0; ni < 4; ++ni) {
      int col = bn + wn * 64 + ni * 16 + lr;
      float bv = bias[col];
#pragma unroll
      for (int mi = 0; mi < 4; ++mi)
#pragma unroll
        for (int r = 0; r < 4; ++r) {
          int rowg = bm + wm * 64 + mi * 16 + lq * 4 + r;
          outF[(size_t)rowg * 256 + col] =
              acc[mi][ni][r] + bv + posP[(size_t)(rowg & (D_S - 1)) * 256 + col];
        }
    }
  }
}

// ================= kexp: in-place kp = ratio*(exp(xp - diag - mx) + eps) =================
__global__ __launch_bounds__(256) void kexp_kernel(
    u16* __restrict__ xp, const u16* __restrict__ dg,
    const unsigned int* __restrict__ kmaxk) {
  size_t i = ((size_t)blockIdx.x * 256 + threadIdx.x) * 8;
  int t = (int)(i >> 9), m0 = (int)(i & 511);
  int head = m0 >> 6, b = t >> 13;
  float dgv = bf2f(dg[(size_t)t * 16 + head]);
  unsigned int mk = kmaxk[b * 8 + head];
  float mx = __uint_as_float((mk & 0x80000000u) ? (mk & 0x7fffffffu) : ~mk);
  u16 vv[8];
  *(uint4*)vv = *(const uint4*)(xp + i);
#pragma unroll
  for (int j = 0; j < 8; ++j)
    vv[j] = f2bf(RATIO * (__expf(bf2f(vv[j]) - dgv - mx) + KEPS));
  *(uint4*)(xp + i) = *(uint4*)vv;
}

// ===== ctxaccum: per (bh-local, chunk of 512): part[m][e] = sum_n kp*v; partk[m] = sum kp =====
__global__ __launch_bounds__(256) void ctxaccum_kernel(
    const u16* __restrict__ kp, const u16* __restrict__ v,
    float* __restrict__ part, float* __restrict__ partk, int hf) {
  __shared__ float kpS[64 * 64];
  __shared__ float vS[64 * 32];
  int tid = threadIdx.x;
  int bl = blockIdx.x >> 3, head = blockIdx.x & 7, c = blockIdx.y;
  int n0l = bl * 8192 + c * 512;   // within half (32768 tokens)
  int bhg = (hf * 4 + bl) * 8 + head;
  int m = tid & 63, eg = tid >> 6;
  float acc[8] = {};
  float ks = 0.f;
  const u16* kpb = kp + (size_t)(hf * 32768 + n0l) * 512 + head * 64;
  const u16* vb = v + (size_t)n0l * 256 + head * 32;
  for (int tile = 0; tile < 8; ++tile) {
    int nb = tile * 64;
    __syncthreads();
#pragma unroll
    for (int i = 0; i < 2; ++i) {
      int idx8 = tid + i * 256;          // 512 chunks of 8
      int row = idx8 >> 3, c8 = (idx8 & 7) * 8;
      u16 tmp[8];
      *(uint4*)tmp = *(const uint4*)(kpb + (size_t)(nb + row) * 512 + c8);
#pragma unroll
      for (int j = 0; j < 8; ++j) kpS[row * 64 + c8 + j] = bf2f(tmp[j]);
    }
    {
      int row = tid >> 2, c8 = (tid & 3) * 8;
      u16 tmp[8];
      *(uint4*)tmp = *(const uint4*)(vb + (size_t)(nb + row) * 256 + c8);
#pragma unroll
      for (int j = 0; j < 8; ++j) vS[row * 32 + c8 + j] = bf2f(tmp[j]);
    }
    __syncthreads();
#pragma unroll 4
    for (int n = 0; n < 64; ++n) {
      float kv = kpS[n * 64 + m];
      if (eg == 0) ks += kv;
      const float* vr = &vS[n * 32 + eg * 8];
#pragma unroll
      for (int j = 0; j < 8; ++j) acc[j] += kv * vr[j];
    }
  }
  float* pp = part + ((size_t)bhg * 16 + c) * 2048 + m * 32 + eg * 8;
#pragma unroll
  for (int j = 0; j < 8; ++j) pp[j] = acc[j];
  if (eg == 0) partk[((size_t)bhg * 16 + c) * 64 + m] = ks;
}

__global__ __launch_bounds__(256) void ctxreduce_kernel(
    const float* __restrict__ part, const float* __restrict__ partk,
    float* __restrict__ ctx, float* __restrict__ ksum) {
  int bh = blockIdx.x, tid = threadIdx.x;
#pragma unroll
  for (int i = 0; i < 8; ++i) {
    int idx = tid + i * 256;
    float s = 0.f;
#pragma unroll
    for (int cc = 0; cc < 16; ++cc)
      s += part[((size_t)bh * 16 + cc) * 2048 + idx];
    ctx[(size_t)bh * 2048 + idx] = s;
  }
  if (tid < 64) {
    float s = 0.f;
#pragma unroll
    for (int cc = 0; cc < 16; ++cc) s += partk[((size_t)bh * 16 + cc) * 64 + tid];
    ksum[bh * 64 + tid] = s;
  }
}

// ================= attnout: ao = (qp@ctx)/(qp@ksum), bf16 out =================
__global__ __launch_bounds__(256) void attnout_kernel(
    const u16* __restrict__ qp, const float* __restrict__ ctx,
    const float* __restrict__ ksum, u16* __restrict__ ao, int hf) {
  __shared__ float ctxS[2048];
  __shared__ float ksS[64];
  __shared__ float qpS[64 * 64];
  int tid = threadIdx.x;
  int rb = blockIdx.x, head = blockIdx.y;
  int n0l = rb * 64;
  int t0g = hf * 32768 + n0l;
  int bhg = (t0g >> 13) * 8 + head;
#pragma unroll
  for (int i = 0; i < 8; ++i) ctxS[tid + i * 256] = ctx[(size_t)bhg * 2048 + tid + i * 256];
  if (tid < 64) ksS[tid] = ksum[bhg * 64 + tid];
#pragma unroll
  for (int i = 0; i < 16; ++i) {
    int idx = tid + i * 256;
    qpS[idx] = bf2f(qp[(size_t)(t0g + (idx >> 6)) * 512 + head * 64 + (idx & 63)]);
  }
  __syncthreads();
  int e = tid & 31, tg = tid >> 5;
#pragma unroll
  for (int it = 0; it < 8; ++it) {
    int t = it * 8 + tg;
    float num = 0.f, den = 0.f;
#pragma unroll
    for (int m = 0; m < 64; ++m) {
      float qv = qpS[t * 64 + m];
      num += qv * ctxS[m * 32 + e];
      den += qv * ksS[m];
    }
    ao[(size_t)(n0l + t) * 256 + head * 32 + e] = f2bf(num / den);
  }
}

// ================= mean pool + final FC (fp32 h) =================
__global__ __launch_bounds__(256) void pool_kernel(
    const float* __restrict__ h, float* __restrict__ pooled) {
  int b = blockIdx.x, chunk = blockIdx.y, j = threadIdx.x;
  const float* hp = h + (size_t)(b * D_S + chunk * 256) * 256 + j;
  float acc = 0.f;
#pragma unroll 4
  for (int s = 0; s < 256; ++s) acc += hp[(size_t)s * 256];
  atomicAdd(pooled + b * 256 + j, acc);
}

__global__ __launch_bounds__(64) void final_kernel(
    const float* __restrict__ pooled, const float* __restrict__ fcw,
    const float* __restrict__ fcb, float* __restrict__ out) {
  int tid = threadIdx.x;
  if (tid >= 16) return;
  int b = tid >> 1, c = tid & 1;
  float acc = 0.f;
  for (int j = 0; j < 256; ++j) acc += pooled[b * 256 + j] * fcw[j * 2 + c];
  out[b * 2 + c] = acc * (1.f / 8192.f) + fcb[c];
}

extern "C" void kernel_launch(void* const* d_in, const int* in_sizes, int n_in,
                              void* d_out, int out_size, void* d_ws, size_t ws_size,
                              hipStream_t stream) {
  const float* x     = (const float*)d_in[0];
  const float* emb_w = (const float*)d_in[1];
  const float* emb_b = (const float*)d_in[2];
  const float* pos   = (const float*)d_in[3];
  const float* ln1_g = (const float*)d_in[4];
  const float* ln1_b = (const float*)d_in[5];
  const float* wq    = (const float*)d_in[6];
  const float* wk    = (const float*)d_in[7];
  const float* wv    = (const float*)d_in[8];
  const float* wo    = (const float*)d_in[9];
  const float* bo    = (const float*)d_in[10];
  const float* ln2_g = (const float*)d_in[11];
  const float* ln2_b = (const float*)d_in[12];
  const float* w1    = (const float*)d_in[13];
  const float* b1    = (const float*)d_in[14];
  const float* w2    = (const float*)d_in[15];
  const float* b2    = (const float*)d_in[16];
  const float* proj  = (const float*)d_in[17];
  const float* fc_w  = (const float*)d_in[18];
  const float* fc_b  = (const float*)d_in[19];

  if (ws_size < NEED_BYTES) {
    report_kernel<<<1, 64, 0, stream>>>((float*)d_out, (float)ws_size);
    return;
  }

  float* ws = (float*)d_ws;
  float* h      = ws + OFF_H;
  u16* xnb      = (u16*)(ws + OFF_XNB);
  u16* BIG      = (u16*)(ws + OFF_BIG);
  u16* Vb       = (u16*)(ws + OFF_V);
  u16* WKPt     = (u16*)(ws + OFF_WKP);   // also embWt before the layer loop
  u16* WQPt     = (u16*)(ws + OFF_WQP);
  u16* WKt      = (u16*)(ws + OFF_WK);    // WQt contiguous after -> combined [512][512]
  u16* WQt      = (u16*)(ws + OFF_WQ);
  u16* WVt      = (u16*)(ws + OFF_WV);
  u16* WOt      = (u16*)(ws + OFF_WO);
  u16* W1t      = (u16*)(ws + OFF_W1);
  u16* W2t      = (u16*)(ws + OFF_W2);
  u16* dg       = (u16*)(ws + OFF_DG);
  unsigned int* kmaxk = (unsigned int*)(ws + OFF_KMAX);
  float* part   = ws + OFF_PART;
  float* partk  = ws + OFF_PARTK;
  float* ctx    = ws + OFF_CTX;
  float* ksum   = ws + OFF_KSUM;
  float* pooled = ws + OFF_POOL;

  // ---- embed as MFMA GEMM: xbf(=BIG) [65536][64] @ embWt(=WKPt) [256][128] ----
  xcvt_kernel<<<4096, 256, 0, stream>>>(x, BIG);
  wsplit_kernel<<<64, 256, 0, stream>>>(emb_w, WKPt, 64, 256, 8);
  mfma_gemm<4, 0, 0, 0><<<dim3(512, 2), 256, 0, stream>>>(
      BIG, WKPt, emb_b, pos, nullptr, h, nullptr, nullptr, nullptr, 256, 64);

  for (int l = 0; l < D_L; ++l) {
    const float* pj = proj + l * 2048;
    ln_kernel<<<TOK / 4, 256, 0, stream>>>(h, xnb, ln1_g + l * 256, ln1_b + l * 256);
    wprojsplit_kernel<<<512, 256, 0, stream>>>(wk + l * 65536, pj, WKPt);
    wprojsplit_kernel<<<512, 256, 0, stream>>>(wq + l * 65536, pj, WQPt);
    wsplit2_kernel<<<512, 256, 0, stream>>>(wk + l * 65536, wq + l * 65536, WKt, WQt);
    wsplit2_kernel<<<512, 256, 0, stream>>>(wv + l * 65536, wo + l * 65536, WVt, WOt);
    wsplit_kernel<<<1024, 256, 0, stream>>>(w1 + l * 262144, W1t, 256, 1024, 10);
    wsplit_kernel<<<1024, 256, 0, stream>>>(w2 + l * 262144, W2t, 1024, 256, 8);
    zero_kernel<<<1, 256, 0, stream>>>((float*)kmaxk, 64);

    // combined diag(k)+diag(q): one N=512 GEMM over [WKt|WQt], dg[t][16]
    mfma_gemm<1, 0, 0, 0><<<dim3(512, 4), 256, 0, stream>>>(
        xnb, WKt, nullptr, nullptr, nullptr, nullptr, nullptr, dg, nullptr, 512, 256);
    // xp + global max
    mfma_gemm<2, 0, 0, 1><<<dim3(512, 4), 256, 0, stream>>>(
        xnb, WKPt, nullptr, nullptr, nullptr, nullptr, BIG, nullptr, kmaxk, 512, 256);
    // kp = exp(xp - diag - mx), in place
    kexp_kernel<<<16384, 256, 0, stream>>>(BIG, dg, kmaxk);
    // context accumulation per half
    for (int hf = 0; hf < 2; ++hf) {
      const u16* xh = xnb + (size_t)hf * 32768 * 256;
      mfma_gemm<0, 0, 0, 1><<<dim3(256, 2), 256, 0, stream>>>(
          xh, WVt, nullptr, nullptr, nullptr, nullptr, Vb, nullptr, nullptr, 256, 256);
      ctxaccum_kernel<<<dim3(32, 16), 256, 0, stream>>>(BIG, Vb, part, partk, hf);
    }
    ctxreduce_kernel<<<64, 256, 0, stream>>>(part, partk, ctx, ksum);
    // qp (overwrites BIG; kp dead)
    mfma_gemm<3, 0, 0, 1><<<dim3(512, 4), 256, 0, stream>>>(
        xnb, WQPt, nullptr, nullptr, dg, nullptr, BIG, nullptr, nullptr, 512, 256);
    for (int hf = 0; hf < 2; ++hf) {
      float* hh = h + (size_t)hf * 32768 * 256;
      attnout_kernel<<<dim3(512, 8), 256, 0, stream>>>(BIG, ctx, ksum, Vb, hf);
      mfma_gemm<0, 0, 1, 0><<<dim3(256, 2), 256, 0, stream>>>(
          Vb, WOt, bo + l * 256, nullptr, nullptr, hh, nullptr, nullptr, nullptr, 256, 256);
    }

    ln_kernel<<<TOK / 4, 256, 0, stream>>>(h, xnb, ln2_g + l * 256, ln2_b + l * 256);
    for (int hf = 0; hf < 2; ++hf) {
      const u16* xh = xnb + (size_t)hf * 32768 * 256;
      float* hh = h + (size_t)hf * 32768 * 256;
      mfma_gemm<0, 1, 0, 1><<<dim3(256, 8), 256, 0, stream>>>(
          xh, W1t, b1 + l * 1024, nullptr, nullptr, nullptr, BIG, nullptr, nullptr, 1024, 256);
      mfma_gemm<0, 0, 1, 0><<<dim3(256, 2), 256, 0, stream>>>(
          BIG, W2t, b2 + l * 256, nullptr, nullptr, hh, nullptr, nullptr, nullptr, 256, 1024);
    }
  }

  zero_kernel<<<8, 256, 0, stream>>>(pooled, 2048);
  pool_kernel<<<dim3(8, 32), 256, 0, stream>>>(h, pooled);
  final_kernel<<<1, 64, 0, stream>>>(pooled, fc_w, fc_b, (float*)d_out);
}

// Round 9
// 3048.267 us; speedup vs baseline: 2.7540x; 1.3083x over previous
//
#include <hip/hip_runtime.h>
#include <math.h>

typedef unsigned short u16;
typedef __attribute__((ext_vector_type(8))) short bf16x8;
typedef __attribute__((ext_vector_type(4))) float f32x4;

// ---- problem dims ----
static constexpr int D_S = 8192;
static constexpr int D_L = 4;
static constexpr int TOK = 65536;
static constexpr float NORMALIZER = 0.4204482076268573f;  // 32^-0.25
static constexpr float RATIO = 0.125f;                    // 64^-0.5
static constexpr float KEPS = 1e-4f;

// ---- workspace layout (float slots) ----  (round-5..8 proven layout)
static constexpr size_t OFF_H     = 0;            // 16,777,216 fp32 residual
static constexpr size_t OFF_XNB   = 16777216;     // 8,388,608  bf16 xn [65536][256]
static constexpr size_t OFF_BIG   = 25165824;     // 16,777,216 bf16 xp/kp/qp [65536][512] | FFN mid | xbf
static constexpr size_t OFF_V     = 41943040;     // 4,194,304  bf16 v/ao per-half [32768][256]
static constexpr size_t OFF_WKP   = 46137344;     // 131,072  (single-plane now; also embWt pre-loop)
static constexpr size_t OFF_WQP   = 46268416;     // 131,072
static constexpr size_t OFF_WK    = 46399488;     // 65,536  (WQ contiguous -> combined [512][256] single)
static constexpr size_t OFF_WQ    = 46465024;     // 65,536
static constexpr size_t OFF_WV    = 46530560;     // 65,536
static constexpr size_t OFF_WO    = 46596096;     // 65,536
static constexpr size_t OFF_W1    = 46661632;     // 262,144
static constexpr size_t OFF_W2    = 46923776;     // 262,144
static constexpr size_t OFF_DG    = 47185920;     // 524,288 (bf16 [65536][16]: k-heads 0-7, q-heads 8-15)
static constexpr size_t OFF_KMAX  = 47710208;     // 64
static constexpr size_t OFF_PART  = 47710272;     // 2,097,152 (ctx partials; Bt reuses this after reduce)
static constexpr size_t OFF_PARTK = 49807424;     // 65,536
static constexpr size_t OFF_CTX   = 49872960;     // 131,072
static constexpr size_t OFF_KSUM  = 50004032;     // 4,096
static constexpr size_t OFF_POOL  = 50008128;     // 2,048
static constexpr size_t NEED_BYTES = 200040704;   // proven OK (rounds 5-8)

static constexpr int BTS = 136;  // Bt row stride in u16 (128 + 8 pad: LDS 2-way banks = free)

static __device__ __forceinline__ float bf2f(u16 u) {
  return __uint_as_float(((unsigned int)u) << 16);
}
static __device__ __forceinline__ u16 f2bf(float f) {
  unsigned int u = __float_as_uint(f);
  u = (u + 0x7fffu + ((u >> 16) & 1u)) >> 16;
  return (u16)u;
}
static __device__ __forceinline__ float geluf(float v) {
  return 0.5f * v * (1.f + erff(v * 0.70710678118654752f));
}

__global__ void report_kernel(float* out, float v) {
  if (threadIdx.x < 16) out[threadIdx.x] = v;
}

__global__ __launch_bounds__(256) void zero_kernel(float* p, int n) {
  int i = blockIdx.x * 256 + threadIdx.x;
  if (i < n) p[i] = 0.f;
}

// ================= x -> bf16 =================
__global__ __launch_bounds__(256) void xcvt_kernel(const float* __restrict__ x,
                                                   u16* __restrict__ xb) {
  int i4 = (blockIdx.x * 256 + threadIdx.x) * 4;
  float4 v = *(const float4*)(x + i4);
  u16 o[4] = {f2bf(v.x), f2bf(v.y), f2bf(v.z), f2bf(v.w)};
  *(uint2*)(xb + i4) = *(uint2*)o;
}

// ================= layernorm: fp32 in, bf16 out =================
__global__ __launch_bounds__(256) void ln_kernel(
    const float* __restrict__ src, u16* __restrict__ dst,
    const float* __restrict__ g, const float* __restrict__ b) {
  int wv = threadIdx.x >> 6, lane = threadIdx.x & 63;
  int t = blockIdx.x * 4 + wv;
  const float4 v = *(const float4*)(src + (size_t)t * 256 + lane * 4);
  float s1 = v.x + v.y + v.z + v.w;
  float s2 = v.x * v.x + v.y * v.y + v.z * v.z + v.w * v.w;
  for (int off = 32; off; off >>= 1) {
    s1 += __shfl_xor(s1, off);
    s2 += __shfl_xor(s2, off);
  }
  float mu = s1 * (1.f / 256.f);
  float var = s2 * (1.f / 256.f) - mu * mu;
  float rs = rsqrtf(var + 1e-5f);
  float4 gg = *(const float4*)(g + lane * 4);
  float4 bb = *(const float4*)(b + lane * 4);
  u16 o0 = f2bf((v.x - mu) * rs * gg.x + bb.x);
  u16 o1 = f2bf((v.y - mu) * rs * gg.y + bb.y);
  u16 o2 = f2bf((v.z - mu) * rs * gg.z + bb.z);
  u16 o3 = f2bf((v.w - mu) * rs * gg.w + bb.w);
  uint2 pk;
  pk.x = (unsigned)o0 | ((unsigned)o1 << 16);
  pk.y = (unsigned)o2 | ((unsigned)o3 << 16);
  *(uint2*)(dst + (size_t)t * 256 + lane * 4) = pk;
}

// ===== weight split: fp32 W[K][N] -> bf16 Wt[N][2K] (hi plane, lo plane) =====
__global__ __launch_bounds__(256) void wsplit_kernel(
    const float* __restrict__ W, u16* __restrict__ Wt, int K, int N, int nb) {
  int i = blockIdx.x * 256 + threadIdx.x;
  int k = i >> nb, n = i & (N - 1);
  float val = W[i];
  u16 hi = f2bf(val);
  u16 lo = f2bf(val - bf2f(hi));
  Wt[(size_t)n * 2 * K + k] = hi;
  Wt[(size_t)n * 2 * K + K + k] = lo;
}

// ===== paired hi/lo split for two 256x256 weights (V / Wo) =====
__global__ __launch_bounds__(256) void wsplit2_kernel(
    const float* __restrict__ Wa, const float* __restrict__ Wb,
    u16* __restrict__ Ta, u16* __restrict__ Tb) {
  int i = blockIdx.x * 256 + threadIdx.x;   // 0..131071
  const float* W = (i < 65536) ? Wa : Wb;
  u16* T = (i < 65536) ? Ta : Tb;
  int j = i & 65535;
  int k = j >> 8, n = j & 255;
  float val = W[j];
  u16 hi = f2bf(val);
  u16 lo = f2bf(val - bf2f(hi));
  T[(size_t)n * 512 + k] = hi;
  T[(size_t)n * 512 + 256 + k] = lo;
}

// ===== paired SINGLE-plane split for wk/wq (diag GEMM weights) =====
__global__ __launch_bounds__(256) void wsplit2s_kernel(
    const float* __restrict__ Wa, const float* __restrict__ Wb,
    u16* __restrict__ Ta, u16* __restrict__ Tb) {
  int i = blockIdx.x * 256 + threadIdx.x;   // 0..131071
  const float* W = (i < 65536) ? Wa : Wb;
  u16* T = (i < 65536) ? Ta : Tb;
  int j = i & 65535;
  int k = j >> 8, n = j & 255;
  T[(size_t)n * 256 + k] = f2bf(W[j]);
}

// ===== WKP/WQP build, SINGLE plane: Wt[n=h*64+m][256] =====
__global__ __launch_bounds__(256) void wprojsplit_kernel(
    const float* __restrict__ w, const float* __restrict__ proj,
    u16* __restrict__ Wt) {
  int i = blockIdx.x * 256 + threadIdx.x;   // 131072
  int k = i & 255, n = i >> 8;
  int head = n >> 6, m = n & 63;
  float s = 0.f;
#pragma unroll
  for (int d = 0; d < 32; ++d) s += w[k * 256 + head * 32 + d] * proj[m * 32 + d];
  Wt[(size_t)n * 256 + k] = f2bf(s * NORMALIZER);
}

// ================= MFMA GEMM: 128x128 tile, A bf16 [M][K], Wt bf16 [N][K*KM] =================
// KM=2: hi/lo split weights; KM=1: single-plane.
// EPI: 0 plain (ACT gelu, ACC fp32-acc, OBF bf16 store), 1 per-head diag,
//      2 xp-store+max, 3 qp, 4 embed (bias + pos, fp32 store, N=256)
template <int EPI, int ACT, int ACC, int OBF, int KM>
__global__ __launch_bounds__(256) void mfma_gemm(
    const u16* __restrict__ A, const u16* __restrict__ Wt,
    const float* __restrict__ bias, const float* __restrict__ posP,
    const u16* __restrict__ diagIn,
    float* __restrict__ outF, u16* __restrict__ outB,
    u16* __restrict__ diagOut, unsigned int* __restrict__ kmaxOut,
    int N, int K) {
  __shared__ __align__(16) u16 Als[4096];   // [q][row][8]
  __shared__ __align__(16) u16 Bls[4096];   // [q][col][8]
  const int K2 = K * KM;
  int tid = threadIdx.x;
  int bm = blockIdx.x * 128, bn = blockIdx.y * 128;
  int w = tid >> 6, lane = tid & 63;
  int wm = w >> 1, wn = w & 1;
  int lr = lane & 15, lq = lane >> 4;
  f32x4 acc[4][4];
#pragma unroll
  for (int i = 0; i < 4; ++i)
#pragma unroll
    for (int j = 0; j < 4; ++j) acc[i][j] = (f32x4){0.f, 0.f, 0.f, 0.f};
  int r0 = tid >> 2, q0 = tid & 3;
  for (int k0 = 0; k0 < K2; k0 += 32) {
    int kk = k0 + q0 * 8;
    int gka = kk & (K - 1);
    uint4 a0 = *(const uint4*)(A + (size_t)(bm + r0) * K + gka);
    uint4 a1 = *(const uint4*)(A + (size_t)(bm + r0 + 64) * K + gka);
    uint4 b0 = *(const uint4*)(Wt + (size_t)(bn + r0) * K2 + kk);
    uint4 b1 = *(const uint4*)(Wt + (size_t)(bn + r0 + 64) * K2 + kk);
    __syncthreads();
    ((uint4*)Als)[q0 * 128 + r0] = a0;
    ((uint4*)Als)[q0 * 128 + r0 + 64] = a1;
    ((uint4*)Bls)[q0 * 128 + r0] = b0;
    ((uint4*)Bls)[q0 * 128 + r0 + 64] = b1;
    __syncthreads();
    bf16x8 af[4], bfr[4];
#pragma unroll
    for (int mi = 0; mi < 4; ++mi)
      af[mi] = ((const bf16x8*)Als)[lq * 128 + wm * 64 + mi * 16 + lr];
#pragma unroll
    for (int ni = 0; ni < 4; ++ni)
      bfr[ni] = ((const bf16x8*)Bls)[lq * 128 + wn * 64 + ni * 16 + lr];
#pragma unroll
    for (int mi = 0; mi < 4; ++mi)
#pragma unroll
      for (int ni = 0; ni < 4; ++ni)
        acc[mi][ni] = __builtin_amdgcn_mfma_f32_16x16x32_bf16(af[mi], bfr[ni], acc[mi][ni], 0, 0, 0);
  }
  // ---- epilogues ----  C/D: col = lane&15, row = (lane>>4)*4 + r  [m89-verified]
  if (EPI == 0) {
#pragma unroll
    for (int ni = 0; ni < 4; ++ni) {
      int col = bn + wn * 64 + ni * 16 + lr;
      float bv = bias ? bias[col] : 0.f;
#pragma unroll
      for (int mi = 0; mi < 4; ++mi)
#pragma unroll
        for (int r = 0; r < 4; ++r) {
          int rowg = bm + wm * 64 + mi * 16 + lq * 4 + r;
          float val = acc[mi][ni][r] + bv;
          if (ACT) val = geluf(val);
          size_t o = (size_t)rowg * N + col;
          if (OBF) outB[o] = f2bf(val);
          else if (ACC) outF[o] += val;
          else outF[o] = val;
        }
    }
  }
  if (EPI == 1) {  // diag per head (32 cols); wave spans 2 heads; dg layout [t][16]
    const float c05n2 = 0.5f * NORMALIZER * NORMALIZER;
    int hb = (bn + wn * 64) >> 5;
#pragma unroll
    for (int mi = 0; mi < 4; ++mi) {
      float s0[4] = {0.f, 0.f, 0.f, 0.f}, s1[4] = {0.f, 0.f, 0.f, 0.f};
#pragma unroll
      for (int ni = 0; ni < 4; ++ni)
#pragma unroll
        for (int r = 0; r < 4; ++r) {
          float v = acc[mi][ni][r];
          if (ni < 2) s0[r] += v * v; else s1[r] += v * v;
        }
#pragma unroll
      for (int r = 0; r < 4; ++r) {
        float a = s0[r], b = s1[r];
        a += __shfl_xor(a, 1); a += __shfl_xor(a, 2); a += __shfl_xor(a, 4); a += __shfl_xor(a, 8);
        b += __shfl_xor(b, 1); b += __shfl_xor(b, 2); b += __shfl_xor(b, 4); b += __shfl_xor(b, 8);
        if (lr == 0) {
          int rowg = bm + wm * 64 + mi * 16 + lq * 4 + r;
          diagOut[(size_t)rowg * 16 + hb] = f2bf(c05n2 * a);
          diagOut[(size_t)rowg * 16 + hb + 1] = f2bf(c05n2 * b);
        }
      }
    }
  }
  if (EPI == 2) {  // store bf16 xp + global max per (b, head)
    float mx = -3.4e38f;
#pragma unroll
    for (int mi = 0; mi < 4; ++mi)
#pragma unroll
      for (int ni = 0; ni < 4; ++ni)
#pragma unroll
        for (int r = 0; r < 4; ++r) {
          float v = acc[mi][ni][r];
          mx = fmaxf(mx, v);
          int rowg = bm + wm * 64 + mi * 16 + lq * 4 + r;
          int col = bn + wn * 64 + ni * 16 + lr;
          outB[(size_t)rowg * N + col] = f2bf(v);
        }
#pragma unroll
    for (int off = 1; off < 64; off <<= 1) mx = fmaxf(mx, __shfl_xor(mx, off));
    if (lane == 0) {
      int b = bm >> 13;
      int head = (bn + wn * 64) >> 6;
      unsigned int u = __float_as_uint(mx);
      unsigned int key = (u & 0x80000000u) ? ~u : (u | 0x80000000u);
      atomicMax(kmaxOut + b * 8 + head, key);
    }
  }
  if (EPI == 3) {  // qp: in-wave row-max over the head's 64 cols, then exp; dg q-heads at +8
    int head = (bn + wn * 64) >> 6;
#pragma unroll
    for (int mi = 0; mi < 4; ++mi) {
      float rm[4] = {-3.4e38f, -3.4e38f, -3.4e38f, -3.4e38f};
#pragma unroll
      for (int ni = 0; ni < 4; ++ni)
#pragma unroll
        for (int r = 0; r < 4; ++r) rm[r] = fmaxf(rm[r], acc[mi][ni][r]);
#pragma unroll
      for (int r = 0; r < 4; ++r) {
        float t = rm[r];
        t = fmaxf(t, __shfl_xor(t, 1)); t = fmaxf(t, __shfl_xor(t, 2));
        t = fmaxf(t, __shfl_xor(t, 4)); t = fmaxf(t, __shfl_xor(t, 8));
        rm[r] = t;
      }
#pragma unroll
      for (int r = 0; r < 4; ++r) {
        int rowg = bm + wm * 64 + mi * 16 + lq * 4 + r;
        float dg = bf2f(diagIn[(size_t)rowg * 16 + 8 + head]);
#pragma unroll
        for (int ni = 0; ni < 4; ++ni) {
          int col = bn + wn * 64 + ni * 16 + lr;
          float v = RATIO * (__expf(acc[mi][ni][r] - dg - rm[r]) + KEPS);
          outB[(size_t)rowg * N + col] = f2bf(v);
        }
      }
    }
  }
  if (EPI == 4) {  // embed: + bias + pos, fp32 store (N==256)
#pragma unroll
    for (int ni = 0; ni < 4; ++ni) {
      int col = bn + wn * 64 + ni * 16 + lr;
      float bv = bias[col];
#pragma unroll
      for (int mi = 0; mi < 4; ++mi)
#pragma unroll
        for (int r = 0; r < 4; ++r) {
          int rowg = bm + wm * 64 + mi * 16 + lq * 4 + r;
          outF[(size_t)rowg * 256 + col] =
              acc[mi][ni][r] + bv + posP[(size_t)(rowg & (D_S - 1)) * 256 + col];
        }
    }
  }
}

// ================= kexp: in-place kp = ratio*(exp(xp - diag - mx) + eps) =================
__global__ __launch_bounds__(256) void kexp_kernel(
    u16* __restrict__ xp, const u16* __restrict__ dg,
    const unsigned int* __restrict__ kmaxk) {
  size_t i = ((size_t)blockIdx.x * 256 + threadIdx.x) * 8;
  int t = (int)(i >> 9), m0 = (int)(i & 511);
  int head = m0 >> 6, b = t >> 13;
  float dgv = bf2f(dg[(size_t)t * 16 + head]);
  unsigned int mk = kmaxk[b * 8 + head];
  float mx = __uint_as_float((mk & 0x80000000u) ? (mk & 0x7fffffffu) : ~mk);
  u16 vv[8];
  *(uint4*)vv = *(const uint4*)(xp + i);
#pragma unroll
  for (int j = 0; j < 8; ++j)
    vv[j] = f2bf(RATIO * (__expf(bf2f(vv[j]) - dgv - mx) + KEPS));
  *(uint4*)(xp + i) = *(uint4*)vv;
}

// ===== ctxaccum: per (bh-local, chunk of 512): part[m][e] = sum_n kp*v; partk[m] = sum kp =====
__global__ __launch_bounds__(256) void ctxaccum_kernel(
    const u16* __restrict__ kp, const u16* __restrict__ v,
    float* __restrict__ part, float* __restrict__ partk, int hf) {
  __shared__ float kpS[64 * 64];
  __shared__ float vS[64 * 32];
  int tid = threadIdx.x;
  int bl = blockIdx.x >> 3, head = blockIdx.x & 7, c = blockIdx.y;
  int n0l = bl * 8192 + c * 512;   // within half (32768 tokens)
  int bhg = (hf * 4 + bl) * 8 + head;
  int m = tid & 63, eg = tid >> 6;
  float acc[8] = {};
  float ks = 0.f;
  const u16* kpb = kp + (size_t)(hf * 32768 + n0l) * 512 + head * 64;
  const u16* vb = v + (size_t)n0l * 256 + head * 32;
  for (int tile = 0; tile < 8; ++tile) {
    int nb = tile * 64;
    __syncthreads();
#pragma unroll
    for (int i = 0; i < 2; ++i) {
      int idx8 = tid + i * 256;
      int row = idx8 >> 3, c8 = (idx8 & 7) * 8;
      u16 tmp[8];
      *(uint4*)tmp = *(const uint4*)(kpb + (size_t)(nb + row) * 512 + c8);
#pragma unroll
      for (int j = 0; j < 8; ++j) kpS[row * 64 + c8 + j] = bf2f(tmp[j]);
    }
    {
      int row = tid >> 2, c8 = (tid & 3) * 8;
      u16 tmp[8];
      *(uint4*)tmp = *(const uint4*)(vb + (size_t)(nb + row) * 256 + c8);
#pragma unroll
      for (int j = 0; j < 8; ++j) vS[row * 32 + c8 + j] = bf2f(tmp[j]);
    }
    __syncthreads();
#pragma unroll 4
    for (int n = 0; n < 64; ++n) {
      float kv = kpS[n * 64 + m];
      if (eg == 0) ks += kv;
      const float* vr = &vS[n * 32 + eg * 8];
#pragma unroll
      for (int j = 0; j < 8; ++j) acc[j] += kv * vr[j];
    }
  }
  float* pp = part + ((size_t)bhg * 16 + c) * 2048 + m * 32 + eg * 8;
#pragma unroll
  for (int j = 0; j < 8; ++j) pp[j] = acc[j];
  if (eg == 0) partk[((size_t)bhg * 16 + c) * 64 + m] = ks;
}

__global__ __launch_bounds__(256) void ctxreduce_kernel(
    const float* __restrict__ part, const float* __restrict__ partk,
    float* __restrict__ ctx, float* __restrict__ ksum) {
  int bh = blockIdx.x, tid = threadIdx.x;
#pragma unroll
  for (int i = 0; i < 8; ++i) {
    int idx = tid + i * 256;
    float s = 0.f;
#pragma unroll
    for (int cc = 0; cc < 16; ++cc)
      s += part[((size_t)bh * 16 + cc) * 2048 + idx];
    ctx[(size_t)bh * 2048 + idx] = s;
  }
  if (tid < 64) {
    float s = 0.f;
#pragma unroll
    for (int cc = 0; cc < 16; ++cc) s += partk[((size_t)bh * 16 + cc) * 64 + tid];
    ksum[bh * 64 + tid] = s;
  }
}

// ===== btprep: pack [ctx | ksum | 0] into B-operand hi/lo bf16: Bt[bh][48][BTS] =====
// cols n: 0..31 = ctx[.][n], 32 = ksum, 33..47 = 0.  k2: 0..63 hi, 64..127 lo.
__global__ __launch_bounds__(256) void btprep_kernel(
    const float* __restrict__ ctx, const float* __restrict__ ksum,
    u16* __restrict__ Bt) {
  int bh = blockIdx.x, tid = threadIdx.x;
  for (int idx = tid; idx < 48 * 64; idx += 256) {
    int n = idx >> 6, k = idx & 63;
    float v = 0.f;
    if (n < 32) v = ctx[(size_t)bh * 2048 + k * 32 + n];
    else if (n == 32) v = ksum[bh * 64 + k];
    u16 hi = f2bf(v);
    u16 lo = f2bf(v - bf2f(hi));
    u16* row = Bt + ((size_t)bh * 48 + n) * BTS;
    row[k] = hi;
    row[64 + k] = lo;
  }
}

// ===== attnout via MFMA: ao = (qp@ctx)/(qp@ksum) ; A=qp (reused for hi+lo halves) =====
// grid (256 rb of 128 tokens, 8 heads) per half; block 256 = 4 waves x 32 tokens.
__global__ __launch_bounds__(256) void attnout_kernel(
    const u16* __restrict__ qp, const u16* __restrict__ Bt,
    u16* __restrict__ ao, int hf) {
  __shared__ __align__(16) u16 BtS[48 * BTS];
  int tid = threadIdx.x;
  int rb = blockIdx.x, head = blockIdx.y;
  int t0l = rb * 128;                       // local within half
  int bhg = ((hf * 32768 + t0l) >> 13) * 8 + head;
  {
    const uint4* src = (const uint4*)(Bt + (size_t)bhg * 48 * BTS);
    for (int i = tid; i < 48 * BTS / 8; i += 256) ((uint4*)BtS)[i] = src[i];
  }
  __syncthreads();
  int w = tid >> 6, lane = tid & 63;
  int lr = lane & 15, lq = lane >> 4;
  int tw = t0l + w * 32;                    // wave's 32 tokens (local)
  const u16* qpb = qp + (size_t)(hf * 32768 + tw) * 512 + head * 64;
  bf16x8 af[2][2];
#pragma unroll
  for (int mt = 0; mt < 2; ++mt)
#pragma unroll
    for (int kc = 0; kc < 2; ++kc)
      af[mt][kc] = *(const bf16x8*)(qpb + (size_t)(mt * 16 + lr) * 512 + kc * 32 + lq * 8);
  f32x4 c0[2], c1[2], c2[2];
#pragma unroll
  for (int mt = 0; mt < 2; ++mt) {
    c0[mt] = (f32x4){0.f, 0.f, 0.f, 0.f};
    c1[mt] = (f32x4){0.f, 0.f, 0.f, 0.f};
    c2[mt] = (f32x4){0.f, 0.f, 0.f, 0.f};
  }
#pragma unroll
  for (int kc = 0; kc < 4; ++kc) {          // k2 chunks: 0,1 = hi, 2,3 = lo (A repeats)
    bf16x8 b0 = *(const bf16x8*)(BtS + (size_t)(0 * 16 + lr) * BTS + kc * 32 + lq * 8);
    bf16x8 b1 = *(const bf16x8*)(BtS + (size_t)(1 * 16 + lr) * BTS + kc * 32 + lq * 8);
    bf16x8 b2 = *(const bf16x8*)(BtS + (size_t)(2 * 16 + lr) * BTS + kc * 32 + lq * 8);
#pragma unroll
    for (int mt = 0; mt < 2; ++mt) {
      bf16x8 a = af[mt][kc & 1];
      c0[mt] = __builtin_amdgcn_mfma_f32_16x16x32_bf16(a, b0, c0[mt], 0, 0, 0);
      c1[mt] = __builtin_amdgcn_mfma_f32_16x16x32_bf16(a, b1, c1[mt], 0, 0, 0);
      c2[mt] = __builtin_amdgcn_mfma_f32_16x16x32_bf16(a, b2, c2[mt], 0, 0, 0);
    }
  }
  // C: col = lane&15, row = lq*4+r. den = col 32 -> tile2 col 0 -> lanes lr==0.
#pragma unroll
  for (int mt = 0; mt < 2; ++mt)
#pragma unroll
    for (int r = 0; r < 4; ++r) {
      float den = __shfl(c2[mt][r], lane & 48);
      int rowl = tw + mt * 16 + lq * 4 + r;
      float inv = 1.f / den;
      ao[(size_t)rowl * 256 + head * 32 + lr] = f2bf(c0[mt][r] * inv);
      ao[(size_t)rowl * 256 + head * 32 + 16 + lr] = f2bf(c1[mt][r] * inv);
    }
}

// ================= mean pool + final FC (fp32 h) =================
__global__ __launch_bounds__(256) void pool_kernel(
    const float* __restrict__ h, float* __restrict__ pooled) {
  int b = blockIdx.x, chunk = blockIdx.y, j = threadIdx.x;
  const float* hp = h + (size_t)(b * D_S + chunk * 256) * 256 + j;
  float acc = 0.f;
#pragma unroll 4
  for (int s = 0; s < 256; ++s) acc += hp[(size_t)s * 256];
  atomicAdd(pooled + b * 256 + j, acc);
}

__global__ __launch_bounds__(64) void final_kernel(
    const float* __restrict__ pooled, const float* __restrict__ fcw,
    const float* __restrict__ fcb, float* __restrict__ out) {
  int tid = threadIdx.x;
  if (tid >= 16) return;
  int b = tid >> 1, c = tid & 1;
  float acc = 0.f;
  for (int j = 0; j < 256; ++j) acc += pooled[b * 256 + j] * fcw[j * 2 + c];
  out[b * 2 + c] = acc * (1.f / 8192.f) + fcb[c];
}

extern "C" void kernel_launch(void* const* d_in, const int* in_sizes, int n_in,
                              void* d_out, int out_size, void* d_ws, size_t ws_size,
                              hipStream_t stream) {
  const float* x     = (const float*)d_in[0];
  const float* emb_w = (const float*)d_in[1];
  const float* emb_b = (const float*)d_in[2];
  const float* pos   = (const float*)d_in[3];
  const float* ln1_g = (const float*)d_in[4];
  const float* ln1_b = (const float*)d_in[5];
  const float* wq    = (const float*)d_in[6];
  const float* wk    = (const float*)d_in[7];
  const float* wv    = (const float*)d_in[8];
  const float* wo    = (const float*)d_in[9];
  const float* bo    = (const float*)d_in[10];
  const float* ln2_g = (const float*)d_in[11];
  const float* ln2_b = (const float*)d_in[12];
  const float* w1    = (const float*)d_in[13];
  const float* b1    = (const float*)d_in[14];
  const float* w2    = (const float*)d_in[15];
  const float* b2    = (const float*)d_in[16];
  const float* proj  = (const float*)d_in[17];
  const float* fc_w  = (const float*)d_in[18];
  const float* fc_b  = (const float*)d_in[19];

  if (ws_size < NEED_BYTES) {
    report_kernel<<<1, 64, 0, stream>>>((float*)d_out, (float)ws_size);
    return;
  }

  float* ws = (float*)d_ws;
  float* h      = ws + OFF_H;
  u16* xnb      = (u16*)(ws + OFF_XNB);
  u16* BIG      = (u16*)(ws + OFF_BIG);
  u16* Vb       = (u16*)(ws + OFF_V);
  u16* WKPt     = (u16*)(ws + OFF_WKP);   // single-plane [512][256]; embWt (hi/lo) pre-loop
  u16* WQPt     = (u16*)(ws + OFF_WQP);
  u16* WKt      = (u16*)(ws + OFF_WK);    // combined single-plane [512][256] (WQ contiguous)
  u16* WQt      = (u16*)(ws + OFF_WQ);
  u16* WVt      = (u16*)(ws + OFF_WV);
  u16* WOt      = (u16*)(ws + OFF_WO);
  u16* W1t      = (u16*)(ws + OFF_W1);
  u16* W2t      = (u16*)(ws + OFF_W2);
  u16* dg       = (u16*)(ws + OFF_DG);
  unsigned int* kmaxk = (unsigned int*)(ws + OFF_KMAX);
  float* part   = ws + OFF_PART;
  u16* Bt       = (u16*)(ws + OFF_PART);  // reuses part after ctxreduce
  float* partk  = ws + OFF_PARTK;
  float* ctx    = ws + OFF_CTX;
  float* ksum   = ws + OFF_KSUM;
  float* pooled = ws + OFF_POOL;

  // ---- embed as MFMA GEMM: xbf(=BIG) [65536][64] @ embWt(=WKPt, hi/lo) ----
  xcvt_kernel<<<4096, 256, 0, stream>>>(x, BIG);
  wsplit_kernel<<<64, 256, 0, stream>>>(emb_w, WKPt, 64, 256, 8);
  mfma_gemm<4, 0, 0, 0, 2><<<dim3(512, 2), 256, 0, stream>>>(
      BIG, WKPt, emb_b, pos, nullptr, h, nullptr, nullptr, nullptr, 256, 64);

  for (int l = 0; l < D_L; ++l) {
    const float* pj = proj + l * 2048;
    ln_kernel<<<TOK / 4, 256, 0, stream>>>(h, xnb, ln1_g + l * 256, ln1_b + l * 256);
    wprojsplit_kernel<<<512, 256, 0, stream>>>(wk + l * 65536, pj, WKPt);
    wprojsplit_kernel<<<512, 256, 0, stream>>>(wq + l * 65536, pj, WQPt);
    wsplit2s_kernel<<<512, 256, 0, stream>>>(wk + l * 65536, wq + l * 65536, WKt, WQt);
    wsplit2_kernel<<<512, 256, 0, stream>>>(wv + l * 65536, wo + l * 65536, WVt, WOt);
    wsplit_kernel<<<1024, 256, 0, stream>>>(w1 + l * 262144, W1t, 256, 1024, 10);
    wsplit_kernel<<<1024, 256, 0, stream>>>(w2 + l * 262144, W2t, 1024, 256, 8);
    zero_kernel<<<1, 256, 0, stream>>>((float*)kmaxk, 64);

    // combined diag(k)+diag(q): one N=512 single-plane GEMM, dg[t][16]
    mfma_gemm<1, 0, 0, 0, 1><<<dim3(512, 4), 256, 0, stream>>>(
        xnb, WKt, nullptr, nullptr, nullptr, nullptr, nullptr, dg, nullptr, 512, 256);
    // xp + global max (single-plane WKP)
    mfma_gemm<2, 0, 0, 1, 1><<<dim3(512, 4), 256, 0, stream>>>(
        xnb, WKPt, nullptr, nullptr, nullptr, nullptr, BIG, nullptr, kmaxk, 512, 256);
    // kp = exp(xp - diag - mx), in place
    kexp_kernel<<<16384, 256, 0, stream>>>(BIG, dg, kmaxk);
    // context accumulation per half
    for (int hf = 0; hf < 2; ++hf) {
      const u16* xh = xnb + (size_t)hf * 32768 * 256;
      mfma_gemm<0, 0, 0, 1, 2><<<dim3(256, 2), 256, 0, stream>>>(
          xh, WVt, nullptr, nullptr, nullptr, nullptr, Vb, nullptr, nullptr, 256, 256);
      ctxaccum_kernel<<<dim3(32, 16), 256, 0, stream>>>(BIG, Vb, part, partk, hf);
    }
    ctxreduce_kernel<<<64, 256, 0, stream>>>(part, partk, ctx, ksum);
    btprep_kernel<<<64, 256, 0, stream>>>(ctx, ksum, Bt);
    // qp (overwrites BIG; kp dead), single-plane WQP
    mfma_gemm<3, 0, 0, 1, 1><<<dim3(512, 4), 256, 0, stream>>>(
        xnb, WQPt, nullptr, nullptr, dg, nullptr, BIG, nullptr, nullptr, 512, 256);
    for (int hf = 0; hf < 2; ++hf) {
      float* hh = h + (size_t)hf * 32768 * 256;
      attnout_kernel<<<dim3(256, 8), 256, 0, stream>>>(BIG, Bt, Vb, hf);
      mfma_gemm<0, 0, 1, 0, 2><<<dim3(256, 2), 256, 0, stream>>>(
          Vb, WOt, bo + l * 256, nullptr, nullptr, hh, nullptr, nullptr, nullptr, 256, 256);
    }

    ln_kernel<<<TOK / 4, 256, 0, stream>>>(h, xnb, ln2_g + l * 256, ln2_b + l * 256);
    for (int hf = 0; hf < 2; ++hf) {
      const u16* xh = xnb + (size_t)hf * 32768 * 256;
      float* hh = h + (size_t)hf * 32768 * 256;
      mfma_gemm<0, 1, 0, 1, 2><<<dim3(256, 8), 256, 0, stream>>>(
          xh, W1t, b1 + l * 1024, nullptr, nullptr, nullptr, BIG, nullptr, nullptr, 1024, 256);
      mfma_gemm<0, 0, 1, 0, 2><<<dim3(256, 2), 256, 0, stream>>>(
          BIG, W2t, b2 + l * 256, nullptr, nullptr, hh, nullptr, nullptr, nullptr, 256, 1024);
    }
  }

  zero_kernel<<<8, 256, 0, stream>>>(pooled, 2048);
  pool_kernel<<<dim3(8, 32), 256, 0, stream>>>(h, pooled);
  final_kernel<<<1, 64, 0, stream>>>(pooled, fc_w, fc_b, (float*)d_out);
}

// Round 10
// 2939.774 us; speedup vs baseline: 2.8557x; 1.0369x over previous
//
#include <hip/hip_runtime.h>
#include <math.h>

typedef unsigned short u16;
typedef __attribute__((ext_vector_type(8))) short bf16x8;
typedef __attribute__((ext_vector_type(4))) float f32x4;

// ---- problem dims ----
static constexpr int D_S = 8192;
static constexpr int D_L = 4;
static constexpr int TOK = 65536;
static constexpr float NORMALIZER = 0.4204482076268573f;  // 32^-0.25
static constexpr float RATIO = 0.125f;                    // 64^-0.5
static constexpr float KEPS = 1e-4f;

// ---- workspace layout (float slots) ----  (round-5..9 proven layout)
static constexpr size_t OFF_H     = 0;            // 16,777,216 fp32 residual
static constexpr size_t OFF_XNB   = 16777216;     // 8,388,608  bf16 xn [65536][256]
static constexpr size_t OFF_BIG   = 25165824;     // 16,777,216 bf16 xp/qp [65536][512] | FFN mid | xbf
static constexpr size_t OFF_V     = 41943040;     // 4,194,304  bf16 v/ao per-half [32768][256]
static constexpr size_t OFF_WKP   = 46137344;     // 131,072  single-plane [512][256]; embWt pre-loop
static constexpr size_t OFF_WQP   = 46268416;     // 131,072
static constexpr size_t OFF_WK    = 46399488;     // 65,536  (WQ contiguous -> combined [512][256] single)
static constexpr size_t OFF_WQ    = 46465024;     // 65,536
static constexpr size_t OFF_WV    = 46530560;     // 65,536
static constexpr size_t OFF_WO    = 46596096;     // 65,536
static constexpr size_t OFF_W1    = 46661632;     // 262,144
static constexpr size_t OFF_W2    = 46923776;     // 262,144
static constexpr size_t OFF_DG    = 47185920;     // 524,288 (bf16 [65536][16]: k-heads 0-7, q-heads 8-15)
static constexpr size_t OFF_KMAX  = 47710208;     // 64
static constexpr size_t OFF_PART  = 47710272;     // 2,097,152 (ctx partials; Bt reuses after reduce)
static constexpr size_t OFF_PARTK = 49807424;     // 65,536
static constexpr size_t OFF_CTX   = 49872960;     // 131,072
static constexpr size_t OFF_KSUM  = 50004032;     // 4,096
static constexpr size_t OFF_POOL  = 50008128;     // 2,048
static constexpr size_t NEED_BYTES = 200040704;   // proven OK (rounds 5-9)

static constexpr int BTS = 136;  // Bt row stride in u16 (128 + 8 pad)

static __device__ __forceinline__ float bf2f(u16 u) {
  return __uint_as_float(((unsigned int)u) << 16);
}
static __device__ __forceinline__ u16 f2bf(float f) {
  unsigned int u = __float_as_uint(f);
  u = (u + 0x7fffu + ((u >> 16) & 1u)) >> 16;
  return (u16)u;
}
static __device__ __forceinline__ float geluf(float v) {
  return 0.5f * v * (1.f + erff(v * 0.70710678118654752f));
}
static __device__ __forceinline__ float dec_max(unsigned int mk) {
  return __uint_as_float((mk & 0x80000000u) ? (mk & 0x7fffffffu) : ~mk);
}

__global__ void report_kernel(float* out, float v) {
  if (threadIdx.x < 16) out[threadIdx.x] = v;
}

__global__ __launch_bounds__(256) void zero_kernel(float* p, int n) {
  int i = blockIdx.x * 256 + threadIdx.x;
  if (i < n) p[i] = 0.f;
}

// ================= x -> bf16 =================
__global__ __launch_bounds__(256) void xcvt_kernel(const float* __restrict__ x,
                                                   u16* __restrict__ xb) {
  int i4 = (blockIdx.x * 256 + threadIdx.x) * 4;
  float4 v = *(const float4*)(x + i4);
  u16 o[4] = {f2bf(v.x), f2bf(v.y), f2bf(v.z), f2bf(v.w)};
  *(uint2*)(xb + i4) = *(uint2*)o;
}

// ================= layernorm: fp32 in, bf16 out =================
__global__ __launch_bounds__(256) void ln_kernel(
    const float* __restrict__ src, u16* __restrict__ dst,
    const float* __restrict__ g, const float* __restrict__ b) {
  int wv = threadIdx.x >> 6, lane = threadIdx.x & 63;
  int t = blockIdx.x * 4 + wv;
  const float4 v = *(const float4*)(src + (size_t)t * 256 + lane * 4);
  float s1 = v.x + v.y + v.z + v.w;
  float s2 = v.x * v.x + v.y * v.y + v.z * v.z + v.w * v.w;
  for (int off = 32; off; off >>= 1) {
    s1 += __shfl_xor(s1, off);
    s2 += __shfl_xor(s2, off);
  }
  float mu = s1 * (1.f / 256.f);
  float var = s2 * (1.f / 256.f) - mu * mu;
  float rs = rsqrtf(var + 1e-5f);
  float4 gg = *(const float4*)(g + lane * 4);
  float4 bb = *(const float4*)(b + lane * 4);
  u16 o0 = f2bf((v.x - mu) * rs * gg.x + bb.x);
  u16 o1 = f2bf((v.y - mu) * rs * gg.y + bb.y);
  u16 o2 = f2bf((v.z - mu) * rs * gg.z + bb.z);
  u16 o3 = f2bf((v.w - mu) * rs * gg.w + bb.w);
  uint2 pk;
  pk.x = (unsigned)o0 | ((unsigned)o1 << 16);
  pk.y = (unsigned)o2 | ((unsigned)o3 << 16);
  *(uint2*)(dst + (size_t)t * 256 + lane * 4) = pk;
}

// ===== embed weight split (hi/lo), used once pre-loop =====
__global__ __launch_bounds__(256) void wsplit_kernel(
    const float* __restrict__ W, u16* __restrict__ Wt, int K, int N, int nb) {
  int i = blockIdx.x * 256 + threadIdx.x;
  int k = i >> nb, n = i & (N - 1);
  float val = W[i];
  u16 hi = f2bf(val);
  u16 lo = f2bf(val - bf2f(hi));
  Wt[(size_t)n * 2 * K + k] = hi;
  Wt[(size_t)n * 2 * K + K + k] = lo;
}

// ===== merged per-layer weight prep: WKP/WQP (proj-folded, single), WKt/WQt (single),
//       WVt/WOt (hi/lo), W1t/W2t (hi/lo), kmax zero.  grid 4096 x 256. =====
__global__ __launch_bounds__(256) void wprep_kernel(
    const float* __restrict__ wk, const float* __restrict__ wq,
    const float* __restrict__ wv, const float* __restrict__ wo,
    const float* __restrict__ w1, const float* __restrict__ w2,
    const float* __restrict__ proj,
    u16* __restrict__ WKP, u16* __restrict__ WQP,
    u16* __restrict__ WKt, u16* __restrict__ WQt,
    u16* __restrict__ WVt, u16* __restrict__ WOt,
    u16* __restrict__ W1t, u16* __restrict__ W2t,
    unsigned int* __restrict__ kmaxk) {
  int gi = blockIdx.x * 256 + threadIdx.x;
  if (gi < 64) kmaxk[gi] = 0u;
  if (gi < 262144) {  // WKP / WQP: proj-folded single-plane
    int i = gi & 131071;
    const float* w = (gi < 131072) ? wk : wq;
    u16* Wt = (gi < 131072) ? WKP : WQP;
    int k = i & 255, n = i >> 8;
    int head = n >> 6, m = n & 63;
    float s = 0.f;
#pragma unroll
    for (int d = 0; d < 32; ++d) s += w[k * 256 + head * 32 + d] * proj[m * 32 + d];
    Wt[(size_t)n * 256 + k] = f2bf(s * NORMALIZER);
  } else if (gi < 393216) {  // WKt / WQt single-plane
    int i = gi - 262144;
    const float* W = (i < 65536) ? wk : wq;
    u16* T = (i < 65536) ? WKt : WQt;
    int j = i & 65535;
    int k = j >> 8, n = j & 255;
    T[(size_t)n * 256 + k] = f2bf(W[j]);
  } else if (gi < 524288) {  // WVt / WOt hi/lo
    int i = gi - 393216;
    const float* W = (i < 65536) ? wv : wo;
    u16* T = (i < 65536) ? WVt : WOt;
    int j = i & 65535;
    int k = j >> 8, n = j & 255;
    float val = W[j];
    u16 hi = f2bf(val);
    u16 lo = f2bf(val - bf2f(hi));
    T[(size_t)n * 512 + k] = hi;
    T[(size_t)n * 512 + 256 + k] = lo;
  } else if (gi < 786432) {  // W1 hi/lo: K=256, N=1024
    int i = gi - 524288;
    int k = i >> 10, n = i & 1023;
    float val = w1[i];
    u16 hi = f2bf(val);
    u16 lo = f2bf(val - bf2f(hi));
    W1t[(size_t)n * 512 + k] = hi;
    W1t[(size_t)n * 512 + 256 + k] = lo;
  } else {                   // W2 hi/lo: K=1024, N=256
    int i = gi - 786432;
    int k = i >> 8, n = i & 255;
    float val = w2[i];
    u16 hi = f2bf(val);
    u16 lo = f2bf(val - bf2f(hi));
    W2t[(size_t)n * 2048 + k] = hi;
    W2t[(size_t)n * 2048 + 1024 + k] = lo;
  }
}

// ================= MFMA GEMM: 128x128 tile, A bf16 [M][K], Wt bf16 [N][K*KM] =================
// KM=2: hi/lo split weights; KM=1: single-plane.
// EPI: 0 plain (ACT gelu, ACC fp32-acc, OBF bf16 store), 3 qp, 4 embed,
//      6 fused xp(y<4: store+max over Wt)+diag(y>=4: over Wt2)
template <int EPI, int ACT, int ACC, int OBF, int KM>
__global__ __launch_bounds__(256) void mfma_gemm(
    const u16* __restrict__ A, const u16* __restrict__ Wt,
    const u16* __restrict__ Wt2,
    const float* __restrict__ bias, const float* __restrict__ posP,
    const u16* __restrict__ diagIn,
    float* __restrict__ outF, u16* __restrict__ outB,
    u16* __restrict__ diagOut, unsigned int* __restrict__ kmaxOut,
    int N, int K) {
  __shared__ __align__(16) u16 Als[4096];   // [q][row][8]
  __shared__ __align__(16) u16 Bls[4096];   // [q][col][8]
  const int K2 = K * KM;
  int tid = threadIdx.x;
  int yb = blockIdx.y;
  int bm = blockIdx.x * 128;
  const u16* Wp = Wt;
  int bn = yb * 128;
  if (EPI == 6 && yb >= 4) { Wp = Wt2; bn = (yb - 4) * 128; }
  int w = tid >> 6, lane = tid & 63;
  int wm = w >> 1, wn = w & 1;
  int lr = lane & 15, lq = lane >> 4;
  f32x4 acc[4][4];
#pragma unroll
  for (int i = 0; i < 4; ++i)
#pragma unroll
    for (int j = 0; j < 4; ++j) acc[i][j] = (f32x4){0.f, 0.f, 0.f, 0.f};
  int r0 = tid >> 2, q0 = tid & 3;
  for (int k0 = 0; k0 < K2; k0 += 32) {
    int kk = k0 + q0 * 8;
    int gka = kk & (K - 1);
    uint4 a0 = *(const uint4*)(A + (size_t)(bm + r0) * K + gka);
    uint4 a1 = *(const uint4*)(A + (size_t)(bm + r0 + 64) * K + gka);
    uint4 b0 = *(const uint4*)(Wp + (size_t)(bn + r0) * K2 + kk);
    uint4 b1 = *(const uint4*)(Wp + (size_t)(bn + r0 + 64) * K2 + kk);
    __syncthreads();
    ((uint4*)Als)[q0 * 128 + r0] = a0;
    ((uint4*)Als)[q0 * 128 + r0 + 64] = a1;
    ((uint4*)Bls)[q0 * 128 + r0] = b0;
    ((uint4*)Bls)[q0 * 128 + r0 + 64] = b1;
    __syncthreads();
    bf16x8 af[4], bfr[4];
#pragma unroll
    for (int mi = 0; mi < 4; ++mi)
      af[mi] = ((const bf16x8*)Als)[lq * 128 + wm * 64 + mi * 16 + lr];
#pragma unroll
    for (int ni = 0; ni < 4; ++ni)
      bfr[ni] = ((const bf16x8*)Bls)[lq * 128 + wn * 64 + ni * 16 + lr];
#pragma unroll
    for (int mi = 0; mi < 4; ++mi)
#pragma unroll
      for (int ni = 0; ni < 4; ++ni)
        acc[mi][ni] = __builtin_amdgcn_mfma_f32_16x16x32_bf16(af[mi], bfr[ni], acc[mi][ni], 0, 0, 0);
  }
  // ---- epilogues ----  C/D: col = lane&15, row = (lane>>4)*4 + r  [m89-verified]
  if (EPI == 0) {
#pragma unroll
    for (int ni = 0; ni < 4; ++ni) {
      int col = bn + wn * 64 + ni * 16 + lr;
      float bv = bias ? bias[col] : 0.f;
#pragma unroll
      for (int mi = 0; mi < 4; ++mi)
#pragma unroll
        for (int r = 0; r < 4; ++r) {
          int rowg = bm + wm * 64 + mi * 16 + lq * 4 + r;
          float val = acc[mi][ni][r] + bv;
          if (ACT) val = geluf(val);
          size_t o = (size_t)rowg * N + col;
          if (OBF) outB[o] = f2bf(val);
          else if (ACC) outF[o] += val;
          else outF[o] = val;
        }
    }
  }
  if (EPI == 3) {  // qp: in-wave row-max over the head's 64 cols, then exp; dg q-heads at +8
    int head = (bn + wn * 64) >> 6;
#pragma unroll
    for (int mi = 0; mi < 4; ++mi) {
      float rm[4] = {-3.4e38f, -3.4e38f, -3.4e38f, -3.4e38f};
#pragma unroll
      for (int ni = 0; ni < 4; ++ni)
#pragma unroll
        for (int r = 0; r < 4; ++r) rm[r] = fmaxf(rm[r], acc[mi][ni][r]);
#pragma unroll
      for (int r = 0; r < 4; ++r) {
        float t = rm[r];
        t = fmaxf(t, __shfl_xor(t, 1)); t = fmaxf(t, __shfl_xor(t, 2));
        t = fmaxf(t, __shfl_xor(t, 4)); t = fmaxf(t, __shfl_xor(t, 8));
        rm[r] = t;
      }
#pragma unroll
      for (int r = 0; r < 4; ++r) {
        int rowg = bm + wm * 64 + mi * 16 + lq * 4 + r;
        float dg = bf2f(diagIn[(size_t)rowg * 16 + 8 + head]);
#pragma unroll
        for (int ni = 0; ni < 4; ++ni) {
          int col = bn + wn * 64 + ni * 16 + lr;
          float v = RATIO * (__expf(acc[mi][ni][r] - dg - rm[r]) + KEPS);
          outB[(size_t)rowg * N + col] = f2bf(v);
        }
      }
    }
  }
  if (EPI == 4) {  // embed: + bias + pos, fp32 store (N==256)
#pragma unroll
    for (int ni = 0; ni < 4; ++ni) {
      int col = bn + wn * 64 + ni * 16 + lr;
      float bv = bias[col];
#pragma unroll
      for (int mi = 0; mi < 4; ++mi)
#pragma unroll
        for (int r = 0; r < 4; ++r) {
          int rowg = bm + wm * 64 + mi * 16 + lq * 4 + r;
          outF[(size_t)rowg * 256 + col] =
              acc[mi][ni][r] + bv + posP[(size_t)(rowg & (D_S - 1)) * 256 + col];
        }
    }
  }
  if (EPI == 6) {
    if (yb < 4) {  // xp: store bf16 + global max per (b, head)
      float mx = -3.4e38f;
#pragma unroll
      for (int mi = 0; mi < 4; ++mi)
#pragma unroll
        for (int ni = 0; ni < 4; ++ni)
#pragma unroll
          for (int r = 0; r < 4; ++r) {
            float v = acc[mi][ni][r];
            mx = fmaxf(mx, v);
            int rowg = bm + wm * 64 + mi * 16 + lq * 4 + r;
            int col = bn + wn * 64 + ni * 16 + lr;
            outB[(size_t)rowg * N + col] = f2bf(v);
          }
#pragma unroll
      for (int off = 1; off < 64; off <<= 1) mx = fmaxf(mx, __shfl_xor(mx, off));
      if (lane == 0) {
        int b = bm >> 13;
        int head = (bn + wn * 64) >> 6;
        unsigned int u = __float_as_uint(mx);
        unsigned int key = (u & 0x80000000u) ? ~u : (u | 0x80000000u);
        atomicMax(kmaxOut + b * 8 + head, key);
      }
    } else {  // diag per head (32 cols); wave spans 2 heads; dg layout [t][16]
      const float c05n2 = 0.5f * NORMALIZER * NORMALIZER;
      int hb = (bn + wn * 64) >> 5;
#pragma unroll
      for (int mi = 0; mi < 4; ++mi) {
        float s0[4] = {0.f, 0.f, 0.f, 0.f}, s1[4] = {0.f, 0.f, 0.f, 0.f};
#pragma unroll
        for (int ni = 0; ni < 4; ++ni)
#pragma unroll
          for (int r = 0; r < 4; ++r) {
            float v = acc[mi][ni][r];
            if (ni < 2) s0[r] += v * v; else s1[r] += v * v;
          }
#pragma unroll
        for (int r = 0; r < 4; ++r) {
          float a = s0[r], b = s1[r];
          a += __shfl_xor(a, 1); a += __shfl_xor(a, 2); a += __shfl_xor(a, 4); a += __shfl_xor(a, 8);
          b += __shfl_xor(b, 1); b += __shfl_xor(b, 2); b += __shfl_xor(b, 4); b += __shfl_xor(b, 8);
          if (lr == 0) {
            int rowg = bm + wm * 64 + mi * 16 + lq * 4 + r;
            diagOut[(size_t)rowg * 16 + hb] = f2bf(c05n2 * a);
            diagOut[(size_t)rowg * 16 + hb + 1] = f2bf(c05n2 * b);
          }
        }
      }
    }
  }
}

// ===== ctxaccum: kp computed inline from raw xp (exp fused); part[m][e] = sum kp*v =====
__global__ __launch_bounds__(256) void ctxaccum_kernel(
    const u16* __restrict__ xp, const u16* __restrict__ v,
    const u16* __restrict__ dg, const unsigned int* __restrict__ kmaxk,
    float* __restrict__ part, float* __restrict__ partk, int hf) {
  __shared__ float kpS[64 * 64];
  __shared__ float vS[64 * 32];
  int tid = threadIdx.x;
  int bl = blockIdx.x >> 3, head = blockIdx.x & 7, c = blockIdx.y;
  int n0l = bl * 8192 + c * 512;   // within half (32768 tokens)
  int bhg = (hf * 4 + bl) * 8 + head;
  int tg0 = hf * 32768 + n0l;
  float mx = dec_max(kmaxk[bhg]);
  int m = tid & 63, eg = tid >> 6;
  float acc[8] = {};
  float ks = 0.f;
  const u16* kpb = xp + (size_t)tg0 * 512 + head * 64;
  const u16* vb = v + (size_t)n0l * 256 + head * 32;
  for (int tile = 0; tile < 8; ++tile) {
    int nb = tile * 64;
    __syncthreads();
#pragma unroll
    for (int i = 0; i < 2; ++i) {
      int idx8 = tid + i * 256;          // 512 chunks of 8
      int row = idx8 >> 3, c8 = (idx8 & 7) * 8;
      float dgrow = bf2f(dg[(size_t)(tg0 + nb + row) * 16 + head]);
      u16 tmp[8];
      *(uint4*)tmp = *(const uint4*)(kpb + (size_t)(nb + row) * 512 + c8);
#pragma unroll
      for (int j = 0; j < 8; ++j)
        kpS[row * 64 + c8 + j] = RATIO * (__expf(bf2f(tmp[j]) - dgrow - mx) + KEPS);
    }
    {
      int row = tid >> 2, c8 = (tid & 3) * 8;
      u16 tmp[8];
      *(uint4*)tmp = *(const uint4*)(vb + (size_t)(nb + row) * 256 + c8);
#pragma unroll
      for (int j = 0; j < 8; ++j) vS[row * 32 + c8 + j] = bf2f(tmp[j]);
    }
    __syncthreads();
#pragma unroll 4
    for (int n = 0; n < 64; ++n) {
      float kv = kpS[n * 64 + m];
      if (eg == 0) ks += kv;
      const float* vr = &vS[n * 32 + eg * 8];
#pragma unroll
      for (int j = 0; j < 8; ++j) acc[j] += kv * vr[j];
    }
  }
  float* pp = part + ((size_t)bhg * 16 + c) * 2048 + m * 32 + eg * 8;
#pragma unroll
  for (int j = 0; j < 8; ++j) pp[j] = acc[j];
  if (eg == 0) partk[((size_t)bhg * 16 + c) * 64 + m] = ks;
}

__global__ __launch_bounds__(256) void ctxreduce_kernel(
    const float* __restrict__ part, const float* __restrict__ partk,
    float* __restrict__ ctx, float* __restrict__ ksum) {
  int bh = blockIdx.x, tid = threadIdx.x;
#pragma unroll
  for (int i = 0; i < 8; ++i) {
    int idx = tid + i * 256;
    float s = 0.f;
#pragma unroll
    for (int cc = 0; cc < 16; ++cc)
      s += part[((size_t)bh * 16 + cc) * 2048 + idx];
    ctx[(size_t)bh * 2048 + idx] = s;
  }
  if (tid < 64) {
    float s = 0.f;
#pragma unroll
    for (int cc = 0; cc < 16; ++cc) s += partk[((size_t)bh * 16 + cc) * 64 + tid];
    ksum[bh * 64 + tid] = s;
  }
}

// ===== btprep: pack [ctx | ksum | 0] into B-operand hi/lo bf16: Bt[bh][48][BTS] =====
__global__ __launch_bounds__(256) void btprep_kernel(
    const float* __restrict__ ctx, const float* __restrict__ ksum,
    u16* __restrict__ Bt) {
  int bh = blockIdx.x, tid = threadIdx.x;
  for (int idx = tid; idx < 48 * 64; idx += 256) {
    int n = idx >> 6, k = idx & 63;
    float v = 0.f;
    if (n < 32) v = ctx[(size_t)bh * 2048 + k * 32 + n];
    else if (n == 32) v = ksum[bh * 64 + k];
    u16 hi = f2bf(v);
    u16 lo = f2bf(v - bf2f(hi));
    u16* row = Bt + ((size_t)bh * 48 + n) * BTS;
    row[k] = hi;
    row[64 + k] = lo;
  }
}

// ===== attnout via MFMA: ao = (qp@ctx)/(qp@ksum) =====
__global__ __launch_bounds__(256) void attnout_kernel(
    const u16* __restrict__ qp, const u16* __restrict__ Bt,
    u16* __restrict__ ao, int hf) {
  __shared__ __align__(16) u16 BtS[48 * BTS];
  int tid = threadIdx.x;
  int rb = blockIdx.x, head = blockIdx.y;
  int t0l = rb * 128;
  int bhg = ((hf * 32768 + t0l) >> 13) * 8 + head;
  {
    const uint4* src = (const uint4*)(Bt + (size_t)bhg * 48 * BTS);
    for (int i = tid; i < 48 * BTS / 8; i += 256) ((uint4*)BtS)[i] = src[i];
  }
  __syncthreads();
  int w = tid >> 6, lane = tid & 63;
  int lr = lane & 15, lq = lane >> 4;
  int tw = t0l + w * 32;
  const u16* qpb = qp + (size_t)(hf * 32768 + tw) * 512 + head * 64;
  bf16x8 af[2][2];
#pragma unroll
  for (int mt = 0; mt < 2; ++mt)
#pragma unroll
    for (int kc = 0; kc < 2; ++kc)
      af[mt][kc] = *(const bf16x8*)(qpb + (size_t)(mt * 16 + lr) * 512 + kc * 32 + lq * 8);
  f32x4 c0[2], c1[2], c2[2];
#pragma unroll
  for (int mt = 0; mt < 2; ++mt) {
    c0[mt] = (f32x4){0.f, 0.f, 0.f, 0.f};
    c1[mt] = (f32x4){0.f, 0.f, 0.f, 0.f};
    c2[mt] = (f32x4){0.f, 0.f, 0.f, 0.f};
  }
#pragma unroll
  for (int kc = 0; kc < 4; ++kc) {
    bf16x8 b0 = *(const bf16x8*)(BtS + (size_t)(0 * 16 + lr) * BTS + kc * 32 + lq * 8);
    bf16x8 b1 = *(const bf16x8*)(BtS + (size_t)(1 * 16 + lr) * BTS + kc * 32 + lq * 8);
    bf16x8 b2 = *(const bf16x8*)(BtS + (size_t)(2 * 16 + lr) * BTS + kc * 32 + lq * 8);
#pragma unroll
    for (int mt = 0; mt < 2; ++mt) {
      bf16x8 a = af[mt][kc & 1];
      c0[mt] = __builtin_amdgcn_mfma_f32_16x16x32_bf16(a, b0, c0[mt], 0, 0, 0);
      c1[mt] = __builtin_amdgcn_mfma_f32_16x16x32_bf16(a, b1, c1[mt], 0, 0, 0);
      c2[mt] = __builtin_amdgcn_mfma_f32_16x16x32_bf16(a, b2, c2[mt], 0, 0, 0);
    }
  }
#pragma unroll
  for (int mt = 0; mt < 2; ++mt)
#pragma unroll
    for (int r = 0; r < 4; ++r) {
      float den = __shfl(c2[mt][r], lane & 48);
      int rowl = tw + mt * 16 + lq * 4 + r;
      float inv = 1.f / den;
      ao[(size_t)rowl * 256 + head * 32 + lr] = f2bf(c0[mt][r] * inv);
      ao[(size_t)rowl * 256 + head * 32 + 16 + lr] = f2bf(c1[mt][r] * inv);
    }
}

// ================= mean pool + final FC (fp32 h) =================
__global__ __launch_bounds__(256) void pool_kernel(
    const float* __restrict__ h, float* __restrict__ pooled) {
  int b = blockIdx.x, chunk = blockIdx.y, j = threadIdx.x;
  const float* hp = h + (size_t)(b * D_S + chunk * 256) * 256 + j;
  float acc = 0.f;
#pragma unroll 4
  for (int s = 0; s < 256; ++s) acc += hp[(size_t)s * 256];
  atomicAdd(pooled + b * 256 + j, acc);
}

__global__ __launch_bounds__(64) void final_kernel(
    const float* __restrict__ pooled, const float* __restrict__ fcw,
    const float* __restrict__ fcb, float* __restrict__ out) {
  int tid = threadIdx.x;
  if (tid >= 16) return;
  int b = tid >> 1, c = tid & 1;
  float acc = 0.f;
  for (int j = 0; j < 256; ++j) acc += pooled[b * 256 + j] * fcw[j * 2 + c];
  out[b * 2 + c] = acc * (1.f / 8192.f) + fcb[c];
}

extern "C" void kernel_launch(void* const* d_in, const int* in_sizes, int n_in,
                              void* d_out, int out_size, void* d_ws, size_t ws_size,
                              hipStream_t stream) {
  const float* x     = (const float*)d_in[0];
  const float* emb_w = (const float*)d_in[1];
  const float* emb_b = (const float*)d_in[2];
  const float* pos   = (const float*)d_in[3];
  const float* ln1_g = (const float*)d_in[4];
  const float* ln1_b = (const float*)d_in[5];
  const float* wq    = (const float*)d_in[6];
  const float* wk    = (const float*)d_in[7];
  const float* wv    = (const float*)d_in[8];
  const float* wo    = (const float*)d_in[9];
  const float* bo    = (const float*)d_in[10];
  const float* ln2_g = (const float*)d_in[11];
  const float* ln2_b = (const float*)d_in[12];
  const float* w1    = (const float*)d_in[13];
  const float* b1    = (const float*)d_in[14];
  const float* w2    = (const float*)d_in[15];
  const float* b2    = (const float*)d_in[16];
  const float* proj  = (const float*)d_in[17];
  const float* fc_w  = (const float*)d_in[18];
  const float* fc_b  = (const float*)d_in[19];

  if (ws_size < NEED_BYTES) {
    report_kernel<<<1, 64, 0, stream>>>((float*)d_out, (float)ws_size);
    return;
  }

  float* ws = (float*)d_ws;
  float* h      = ws + OFF_H;
  u16* xnb      = (u16*)(ws + OFF_XNB);
  u16* BIG      = (u16*)(ws + OFF_BIG);
  u16* Vb       = (u16*)(ws + OFF_V);
  u16* WKPt     = (u16*)(ws + OFF_WKP);
  u16* WQPt     = (u16*)(ws + OFF_WQP);
  u16* WKt      = (u16*)(ws + OFF_WK);
  u16* WQt      = (u16*)(ws + OFF_WQ);
  u16* WVt      = (u16*)(ws + OFF_WV);
  u16* WOt      = (u16*)(ws + OFF_WO);
  u16* W1t      = (u16*)(ws + OFF_W1);
  u16* W2t      = (u16*)(ws + OFF_W2);
  u16* dg       = (u16*)(ws + OFF_DG);
  unsigned int* kmaxk = (unsigned int*)(ws + OFF_KMAX);
  float* part   = ws + OFF_PART;
  u16* Bt       = (u16*)(ws + OFF_PART);  // reuses part after ctxreduce (btprep reads ctx/ksum only)
  float* partk  = ws + OFF_PARTK;
  float* ctx    = ws + OFF_CTX;
  float* ksum   = ws + OFF_KSUM;
  float* pooled = ws + OFF_POOL;

  // ---- embed as MFMA GEMM ----
  xcvt_kernel<<<4096, 256, 0, stream>>>(x, BIG);
  wsplit_kernel<<<64, 256, 0, stream>>>(emb_w, WKPt, 64, 256, 8);
  mfma_gemm<4, 0, 0, 0, 2><<<dim3(512, 2), 256, 0, stream>>>(
      BIG, WKPt, nullptr, emb_b, pos, nullptr, h, nullptr, nullptr, nullptr, 256, 64);

  for (int l = 0; l < D_L; ++l) {
    const float* pj = proj + l * 2048;
    ln_kernel<<<TOK / 4, 256, 0, stream>>>(h, xnb, ln1_g + l * 256, ln1_b + l * 256);
    wprep_kernel<<<4096, 256, 0, stream>>>(
        wk + l * 65536, wq + l * 65536, wv + l * 65536, wo + l * 65536,
        w1 + l * 262144, w2 + l * 262144, pj,
        WKPt, WQPt, WKt, WQt, WVt, WOt, W1t, W2t, kmaxk);

    // fused xp(+kmax) and diag(k|q): one launch, y<4 xp / y>=4 diag
    mfma_gemm<6, 0, 0, 1, 1><<<dim3(512, 8), 256, 0, stream>>>(
        xnb, WKPt, WKt, nullptr, nullptr, nullptr, nullptr, BIG, dg, kmaxk, 512, 256);
    // context accumulation per half (exp fused into staging)
    for (int hf = 0; hf < 2; ++hf) {
      const u16* xh = xnb + (size_t)hf * 32768 * 256;
      mfma_gemm<0, 0, 0, 1, 2><<<dim3(256, 2), 256, 0, stream>>>(
          xh, WVt, nullptr, nullptr, nullptr, nullptr, nullptr, Vb, nullptr, nullptr, 256, 256);
      ctxaccum_kernel<<<dim3(32, 16), 256, 0, stream>>>(BIG, Vb, dg, kmaxk, part, partk, hf);
    }
    ctxreduce_kernel<<<64, 256, 0, stream>>>(part, partk, ctx, ksum);
    btprep_kernel<<<64, 256, 0, stream>>>(ctx, ksum, Bt);
    // qp (overwrites BIG; xp dead), single-plane WQP
    mfma_gemm<3, 0, 0, 1, 1><<<dim3(512, 4), 256, 0, stream>>>(
        xnb, WQPt, nullptr, nullptr, nullptr, dg, nullptr, BIG, nullptr, nullptr, 512, 256);
    for (int hf = 0; hf < 2; ++hf) {
      float* hh = h + (size_t)hf * 32768 * 256;
      attnout_kernel<<<dim3(256, 8), 256, 0, stream>>>(BIG, Bt, Vb, hf);
      mfma_gemm<0, 0, 1, 0, 2><<<dim3(256, 2), 256, 0, stream>>>(
          Vb, WOt, nullptr, bo + l * 256, nullptr, nullptr, hh, nullptr, nullptr, nullptr, 256, 256);
    }

    ln_kernel<<<TOK / 4, 256, 0, stream>>>(h, xnb, ln2_g + l * 256, ln2_b + l * 256);
    for (int hf = 0; hf < 2; ++hf) {
      const u16* xh = xnb + (size_t)hf * 32768 * 256;
      float* hh = h + (size_t)hf * 32768 * 256;
      mfma_gemm<0, 1, 0, 1, 2><<<dim3(256, 8), 256, 0, stream>>>(
          xh, W1t, nullptr, b1 + l * 1024, nullptr, nullptr, nullptr, BIG, nullptr, nullptr, 1024, 256);
      mfma_gemm<0, 0, 1, 0, 2><<<dim3(256, 2), 256, 0, stream>>>(
          BIG, W2t, nullptr, b2 + l * 256, nullptr, nullptr, hh, nullptr, nullptr, nullptr, 256, 1024);
    }
  }

  zero_kernel<<<8, 256, 0, stream>>>(pooled, 2048);
  pool_kernel<<<dim3(8, 32), 256, 0, stream>>>(h, pooled);
  final_kernel<<<1, 64, 0, stream>>>(pooled, fc_w, fc_b, (float*)d_out);
}

// Round 11
// 2535.615 us; speedup vs baseline: 3.3109x; 1.1594x over previous
//
#include <hip/hip_runtime.h>
#include <math.h>

typedef unsigned short u16;
typedef __attribute__((ext_vector_type(8))) short bf16x8;
typedef __attribute__((ext_vector_type(4))) float f32x4;

// ---- problem dims ----
static constexpr int D_S = 8192;
static constexpr int D_L = 4;
static constexpr int TOK = 65536;
static constexpr float NORMALIZER = 0.4204482076268573f;  // 32^-0.25
static constexpr float RATIO = 0.125f;                    // 64^-0.5
static constexpr float KEPS = 1e-4f;

// ---- workspace layout (float slots) ----  (round-5..10 proven layout)
static constexpr size_t OFF_H     = 0;            // 16,777,216 fp32 residual
static constexpr size_t OFF_XNB   = 16777216;     // 8,388,608  bf16 xn [65536][256]
static constexpr size_t OFF_BIG   = 25165824;     // 16,777,216 bf16 xp/qp [65536][512] | FFN mid | xbf
static constexpr size_t OFF_V     = 41943040;     // 4,194,304  bf16 v/ao per-half [32768][256]
static constexpr size_t OFF_WKP   = 46137344;     // 131,072  single-plane [512][256]; embWt pre-loop
static constexpr size_t OFF_WQP   = 46268416;     // 131,072
static constexpr size_t OFF_WK    = 46399488;     // 65,536  (WQ contiguous -> combined [512][256] single)
static constexpr size_t OFF_WQ    = 46465024;     // 65,536
static constexpr size_t OFF_WV    = 46530560;     // 65,536
static constexpr size_t OFF_WO    = 46596096;     // 65,536
static constexpr size_t OFF_W1    = 46661632;     // 262,144 (single-plane uses half; region reserved)
static constexpr size_t OFF_W2    = 46923776;     // 262,144
static constexpr size_t OFF_DG    = 47185920;     // 524,288 (bf16 [65536][16]: k-heads 0-7, q-heads 8-15)
static constexpr size_t OFF_KMAX  = 47710208;     // 64
static constexpr size_t OFF_PART  = 47710272;     // 2,097,152 (ctx partials; Bt reuses after reduce)
static constexpr size_t OFF_PARTK = 49807424;     // 65,536
static constexpr size_t OFF_CTX   = 49872960;     // 131,072
static constexpr size_t OFF_KSUM  = 50004032;     // 4,096
static constexpr size_t OFF_POOL  = 50008128;     // 2,048
static constexpr size_t NEED_BYTES = 200040704;   // proven OK (rounds 5-10)

static constexpr int BTS = 136;  // Bt row stride in u16 (128 + 8 pad)

static __device__ __forceinline__ float bf2f(u16 u) {
  return __uint_as_float(((unsigned int)u) << 16);
}
static __device__ __forceinline__ u16 f2bf(float f) {
  unsigned int u = __float_as_uint(f);
  u = (u + 0x7fffu + ((u >> 16) & 1u)) >> 16;
  return (u16)u;
}
static __device__ __forceinline__ float geluf(float v) {
  return 0.5f * v * (1.f + erff(v * 0.70710678118654752f));
}
static __device__ __forceinline__ float dec_max(unsigned int mk) {
  return __uint_as_float((mk & 0x80000000u) ? (mk & 0x7fffffffu) : ~mk);
}

__global__ void report_kernel(float* out, float v) {
  if (threadIdx.x < 16) out[threadIdx.x] = v;
}

__global__ __launch_bounds__(256) void zero_kernel(float* p, int n) {
  int i = blockIdx.x * 256 + threadIdx.x;
  if (i < n) p[i] = 0.f;
}

// ================= x -> bf16 =================
__global__ __launch_bounds__(256) void xcvt_kernel(const float* __restrict__ x,
                                                   u16* __restrict__ xb) {
  int i4 = (blockIdx.x * 256 + threadIdx.x) * 4;
  float4 v = *(const float4*)(x + i4);
  u16 o[4] = {f2bf(v.x), f2bf(v.y), f2bf(v.z), f2bf(v.w)};
  *(uint2*)(xb + i4) = *(uint2*)o;
}

// ================= layernorm: fp32 in, bf16 out =================
__global__ __launch_bounds__(256) void ln_kernel(
    const float* __restrict__ src, u16* __restrict__ dst,
    const float* __restrict__ g, const float* __restrict__ b) {
  int wv = threadIdx.x >> 6, lane = threadIdx.x & 63;
  int t = blockIdx.x * 4 + wv;
  const float4 v = *(const float4*)(src + (size_t)t * 256 + lane * 4);
  float s1 = v.x + v.y + v.z + v.w;
  float s2 = v.x * v.x + v.y * v.y + v.z * v.z + v.w * v.w;
  for (int off = 32; off; off >>= 1) {
    s1 += __shfl_xor(s1, off);
    s2 += __shfl_xor(s2, off);
  }
  float mu = s1 * (1.f / 256.f);
  float var = s2 * (1.f / 256.f) - mu * mu;
  float rs = rsqrtf(var + 1e-5f);
  float4 gg = *(const float4*)(g + lane * 4);
  float4 bb = *(const float4*)(b + lane * 4);
  u16 o0 = f2bf((v.x - mu) * rs * gg.x + bb.x);
  u16 o1 = f2bf((v.y - mu) * rs * gg.y + bb.y);
  u16 o2 = f2bf((v.z - mu) * rs * gg.z + bb.z);
  u16 o3 = f2bf((v.w - mu) * rs * gg.w + bb.w);
  uint2 pk;
  pk.x = (unsigned)o0 | ((unsigned)o1 << 16);
  pk.y = (unsigned)o2 | ((unsigned)o3 << 16);
  *(uint2*)(dst + (size_t)t * 256 + lane * 4) = pk;
}

// ===== embed weight split (hi/lo), used once pre-loop =====
__global__ __launch_bounds__(256) void wsplit_kernel(
    const float* __restrict__ W, u16* __restrict__ Wt, int K, int N, int nb) {
  int i = blockIdx.x * 256 + threadIdx.x;
  int k = i >> nb, n = i & (N - 1);
  float val = W[i];
  u16 hi = f2bf(val);
  u16 lo = f2bf(val - bf2f(hi));
  Wt[(size_t)n * 2 * K + k] = hi;
  Wt[(size_t)n * 2 * K + K + k] = lo;
}

// ===== merged per-layer weight prep: WKP/WQP (proj-folded, single), WKt/WQt (single),
//       WVt/WOt (hi/lo), W1t/W2t (SINGLE-plane this round), kmax zero.  grid 4096 x 256. =====
__global__ __launch_bounds__(256) void wprep_kernel(
    const float* __restrict__ wk, const float* __restrict__ wq,
    const float* __restrict__ wv, const float* __restrict__ wo,
    const float* __restrict__ w1, const float* __restrict__ w2,
    const float* __restrict__ proj,
    u16* __restrict__ WKP, u16* __restrict__ WQP,
    u16* __restrict__ WKt, u16* __restrict__ WQt,
    u16* __restrict__ WVt, u16* __restrict__ WOt,
    u16* __restrict__ W1t, u16* __restrict__ W2t,
    unsigned int* __restrict__ kmaxk) {
  int gi = blockIdx.x * 256 + threadIdx.x;
  if (gi < 64) kmaxk[gi] = 0u;
  if (gi < 262144) {  // WKP / WQP: proj-folded single-plane
    int i = gi & 131071;
    const float* w = (gi < 131072) ? wk : wq;
    u16* Wt = (gi < 131072) ? WKP : WQP;
    int k = i & 255, n = i >> 8;
    int head = n >> 6, m = n & 63;
    float s = 0.f;
#pragma unroll
    for (int d = 0; d < 32; ++d) s += w[k * 256 + head * 32 + d] * proj[m * 32 + d];
    Wt[(size_t)n * 256 + k] = f2bf(s * NORMALIZER);
  } else if (gi < 393216) {  // WKt / WQt single-plane
    int i = gi - 262144;
    const float* W = (i < 65536) ? wk : wq;
    u16* T = (i < 65536) ? WKt : WQt;
    int j = i & 65535;
    int k = j >> 8, n = j & 255;
    T[(size_t)n * 256 + k] = f2bf(W[j]);
  } else if (gi < 524288) {  // WVt / WOt hi/lo
    int i = gi - 393216;
    const float* W = (i < 65536) ? wv : wo;
    u16* T = (i < 65536) ? WVt : WOt;
    int j = i & 65535;
    int k = j >> 8, n = j & 255;
    float val = W[j];
    u16 hi = f2bf(val);
    u16 lo = f2bf(val - bf2f(hi));
    T[(size_t)n * 512 + k] = hi;
    T[(size_t)n * 512 + 256 + k] = lo;
  } else if (gi < 786432) {  // W1 SINGLE-plane: K=256, N=1024
    int i = gi - 524288;
    int k = i >> 10, n = i & 1023;
    W1t[(size_t)n * 256 + k] = f2bf(w1[i]);
  } else {                   // W2 SINGLE-plane: K=1024, N=256
    int i = gi - 786432;
    int k = i >> 8, n = i & 255;
    W2t[(size_t)n * 1024 + k] = f2bf(w2[i]);
  }
}

// ================= MFMA GEMM: 128x128 tile, A bf16 [M][K], Wt bf16 [N][K*KM] =================
// KM=2: hi/lo split weights; KM=1: single-plane.
// EPI: 0 plain (ACT gelu, ACC fp32-acc, OBF bf16 store), 3 qp, 4 embed,
//      6 fused xp(y<4: store+max over Wt)+diag(y>=4: over Wt2)
template <int EPI, int ACT, int ACC, int OBF, int KM>
__global__ __launch_bounds__(256) void mfma_gemm(
    const u16* __restrict__ A, const u16* __restrict__ Wt,
    const u16* __restrict__ Wt2,
    const float* __restrict__ bias, const float* __restrict__ posP,
    const u16* __restrict__ diagIn,
    float* __restrict__ outF, u16* __restrict__ outB,
    u16* __restrict__ diagOut, unsigned int* __restrict__ kmaxOut,
    int N, int K) {
  __shared__ __align__(16) u16 Als[4096];   // [q][row][8]
  __shared__ __align__(16) u16 Bls[4096];   // [q][col][8]
  const int K2 = K * KM;
  int tid = threadIdx.x;
  int yb = blockIdx.y;
  int bm = blockIdx.x * 128;
  const u16* Wp = Wt;
  int bn = yb * 128;
  if (EPI == 6 && yb >= 4) { Wp = Wt2; bn = (yb - 4) * 128; }
  int w = tid >> 6, lane = tid & 63;
  int wm = w >> 1, wn = w & 1;
  int lr = lane & 15, lq = lane >> 4;
  f32x4 acc[4][4];
#pragma unroll
  for (int i = 0; i < 4; ++i)
#pragma unroll
    for (int j = 0; j < 4; ++j) acc[i][j] = (f32x4){0.f, 0.f, 0.f, 0.f};
  int r0 = tid >> 2, q0 = tid & 3;
  for (int k0 = 0; k0 < K2; k0 += 32) {
    int kk = k0 + q0 * 8;
    int gka = kk & (K - 1);
    uint4 a0 = *(const uint4*)(A + (size_t)(bm + r0) * K + gka);
    uint4 a1 = *(const uint4*)(A + (size_t)(bm + r0 + 64) * K + gka);
    uint4 b0 = *(const uint4*)(Wp + (size_t)(bn + r0) * K2 + kk);
    uint4 b1 = *(const uint4*)(Wp + (size_t)(bn + r0 + 64) * K2 + kk);
    __syncthreads();
    ((uint4*)Als)[q0 * 128 + r0] = a0;
    ((uint4*)Als)[q0 * 128 + r0 + 64] = a1;
    ((uint4*)Bls)[q0 * 128 + r0] = b0;
    ((uint4*)Bls)[q0 * 128 + r0 + 64] = b1;
    __syncthreads();
    bf16x8 af[4], bfr[4];
#pragma unroll
    for (int mi = 0; mi < 4; ++mi)
      af[mi] = ((const bf16x8*)Als)[lq * 128 + wm * 64 + mi * 16 + lr];
#pragma unroll
    for (int ni = 0; ni < 4; ++ni)
      bfr[ni] = ((const bf16x8*)Bls)[lq * 128 + wn * 64 + ni * 16 + lr];
#pragma unroll
    for (int mi = 0; mi < 4; ++mi)
#pragma unroll
      for (int ni = 0; ni < 4; ++ni)
        acc[mi][ni] = __builtin_amdgcn_mfma_f32_16x16x32_bf16(af[mi], bfr[ni], acc[mi][ni], 0, 0, 0);
  }
  // ---- epilogues ----  C/D: col = lane&15, row = (lane>>4)*4 + r  [m89-verified]
  if (EPI == 0) {
#pragma unroll
    for (int ni = 0; ni < 4; ++ni) {
      int col = bn + wn * 64 + ni * 16 + lr;
      float bv = bias ? bias[col] : 0.f;
#pragma unroll
      for (int mi = 0; mi < 4; ++mi)
#pragma unroll
        for (int r = 0; r < 4; ++r) {
          int rowg = bm + wm * 64 + mi * 16 + lq * 4 + r;
          float val = acc[mi][ni][r] + bv;
          if (ACT) val = geluf(val);
          size_t o = (size_t)rowg * N + col;
          if (OBF) outB[o] = f2bf(val);
          else if (ACC) outF[o] += val;
          else outF[o] = val;
        }
    }
  }
  if (EPI == 3) {  // qp: in-wave row-max over the head's 64 cols, then exp; dg q-heads at +8
    int head = (bn + wn * 64) >> 6;
#pragma unroll
    for (int mi = 0; mi < 4; ++mi) {
      float rm[4] = {-3.4e38f, -3.4e38f, -3.4e38f, -3.4e38f};
#pragma unroll
      for (int ni = 0; ni < 4; ++ni)
#pragma unroll
        for (int r = 0; r < 4; ++r) rm[r] = fmaxf(rm[r], acc[mi][ni][r]);
#pragma unroll
      for (int r = 0; r < 4; ++r) {
        float t = rm[r];
        t = fmaxf(t, __shfl_xor(t, 1)); t = fmaxf(t, __shfl_xor(t, 2));
        t = fmaxf(t, __shfl_xor(t, 4)); t = fmaxf(t, __shfl_xor(t, 8));
        rm[r] = t;
      }
#pragma unroll
      for (int r = 0; r < 4; ++r) {
        int rowg = bm + wm * 64 + mi * 16 + lq * 4 + r;
        float dg = bf2f(diagIn[(size_t)rowg * 16 + 8 + head]);
#pragma unroll
        for (int ni = 0; ni < 4; ++ni) {
          int col = bn + wn * 64 + ni * 16 + lr;
          float v = RATIO * (__expf(acc[mi][ni][r] - dg - rm[r]) + KEPS);
          outB[(size_t)rowg * N + col] = f2bf(v);
        }
      }
    }
  }
  if (EPI == 4) {  // embed: + bias + pos, fp32 store (N==256)
#pragma unroll
    for (int ni = 0; ni < 4; ++ni) {
      int col = bn + wn * 64 + ni * 16 + lr;
      float bv = bias[col];
#pragma unroll
      for (int mi = 0; mi < 4; ++mi)
#pragma unroll
        for (int r = 0; r < 4; ++r) {
          int rowg = bm + wm * 64 + mi * 16 + lq * 4 + r;
          outF[(size_t)rowg * 256 + col] =
              acc[mi][ni][r] + bv + posP[(size_t)(rowg & (D_S - 1)) * 256 + col];
        }
    }
  }
  if (EPI == 6) {
    if (yb < 4) {  // xp: store bf16 + global max per (b, head)
      float mx = -3.4e38f;
#pragma unroll
      for (int mi = 0; mi < 4; ++mi)
#pragma unroll
        for (int ni = 0; ni < 4; ++ni)
#pragma unroll
          for (int r = 0; r < 4; ++r) {
            float v = acc[mi][ni][r];
            mx = fmaxf(mx, v);
            int rowg = bm + wm * 64 + mi * 16 + lq * 4 + r;
            int col = bn + wn * 64 + ni * 16 + lr;
            outB[(size_t)rowg * N + col] = f2bf(v);
          }
#pragma unroll
      for (int off = 1; off < 64; off <<= 1) mx = fmaxf(mx, __shfl_xor(mx, off));
      if (lane == 0) {
        int b = bm >> 13;
        int head = (bn + wn * 64) >> 6;
        unsigned int u = __float_as_uint(mx);
        unsigned int key = (u & 0x80000000u) ? ~u : (u | 0x80000000u);
        atomicMax(kmaxOut + b * 8 + head, key);
      }
    } else {  // diag per head (32 cols); wave spans 2 heads; dg layout [t][16]
      const float c05n2 = 0.5f * NORMALIZER * NORMALIZER;
      int hb = (bn + wn * 64) >> 5;
#pragma unroll
      for (int mi = 0; mi < 4; ++mi) {
        float s0[4] = {0.f, 0.f, 0.f, 0.f}, s1[4] = {0.f, 0.f, 0.f, 0.f};
#pragma unroll
        for (int ni = 0; ni < 4; ++ni)
#pragma unroll
          for (int r = 0; r < 4; ++r) {
            float v = acc[mi][ni][r];
            if (ni < 2) s0[r] += v * v; else s1[r] += v * v;
          }
#pragma unroll
        for (int r = 0; r < 4; ++r) {
          float a = s0[r], b = s1[r];
          a += __shfl_xor(a, 1); a += __shfl_xor(a, 2); a += __shfl_xor(a, 4); a += __shfl_xor(a, 8);
          b += __shfl_xor(b, 1); b += __shfl_xor(b, 2); b += __shfl_xor(b, 4); b += __shfl_xor(b, 8);
          if (lr == 0) {
            int rowg = bm + wm * 64 + mi * 16 + lq * 4 + r;
            diagOut[(size_t)rowg * 16 + hb] = f2bf(c05n2 * a);
            diagOut[(size_t)rowg * 16 + hb + 1] = f2bf(c05n2 * b);
          }
        }
      }
    }
  }
}

// ===== ctxaccum: kp computed inline from raw xp (exp fused); part[m][e] = sum kp*v =====
__global__ __launch_bounds__(256) void ctxaccum_kernel(
    const u16* __restrict__ xp, const u16* __restrict__ v,
    const u16* __restrict__ dg, const unsigned int* __restrict__ kmaxk,
    float* __restrict__ part, float* __restrict__ partk, int hf) {
  __shared__ float kpS[64 * 64];
  __shared__ float vS[64 * 32];
  int tid = threadIdx.x;
  int bl = blockIdx.x >> 3, head = blockIdx.x & 7, c = blockIdx.y;
  int n0l = bl * 8192 + c * 512;   // within half (32768 tokens)
  int bhg = (hf * 4 + bl) * 8 + head;
  int tg0 = hf * 32768 + n0l;
  float mx = dec_max(kmaxk[bhg]);
  int m = tid & 63, eg = tid >> 6;
  float acc[8] = {};
  float ks = 0.f;
  const u16* kpb = xp + (size_t)tg0 * 512 + head * 64;
  const u16* vb = v + (size_t)n0l * 256 + head * 32;
  for (int tile = 0; tile < 8; ++tile) {
    int nb = tile * 64;
    __syncthreads();
#pragma unroll
    for (int i = 0; i < 2; ++i) {
      int idx8 = tid + i * 256;          // 512 chunks of 8
      int row = idx8 >> 3, c8 = (idx8 & 7) * 8;
      float dgrow = bf2f(dg[(size_t)(tg0 + nb + row) * 16 + head]);
      u16 tmp[8];
      *(uint4*)tmp = *(const uint4*)(kpb + (size_t)(nb + row) * 512 + c8);
#pragma unroll
      for (int j = 0; j < 8; ++j)
        kpS[row * 64 + c8 + j] = RATIO * (__expf(bf2f(tmp[j]) - dgrow - mx) + KEPS);
    }
    {
      int row = tid >> 2, c8 = (tid & 3) * 8;
      u16 tmp[8];
      *(uint4*)tmp = *(const uint4*)(vb + (size_t)(nb + row) * 256 + c8);
#pragma unroll
      for (int j = 0; j < 8; ++j) vS[row * 32 + c8 + j] = bf2f(tmp[j]);
    }
    __syncthreads();
#pragma unroll 4
    for (int n = 0; n < 64; ++n) {
      float kv = kpS[n * 64 + m];
      if (eg == 0) ks += kv;
      const float* vr = &vS[n * 32 + eg * 8];
#pragma unroll
      for (int j = 0; j < 8; ++j) acc[j] += kv * vr[j];
    }
  }
  float* pp = part + ((size_t)bhg * 16 + c) * 2048 + m * 32 + eg * 8;
#pragma unroll
  for (int j = 0; j < 8; ++j) pp[j] = acc[j];
  if (eg == 0) partk[((size_t)bhg * 16 + c) * 64 + m] = ks;
}

__global__ __launch_bounds__(256) void ctxreduce_kernel(
    const float* __restrict__ part, const float* __restrict__ partk,
    float* __restrict__ ctx, float* __restrict__ ksum) {
  int bh = blockIdx.x, tid = threadIdx.x;
#pragma unroll
  for (int i = 0; i < 8; ++i) {
    int idx = tid + i * 256;
    float s = 0.f;
#pragma unroll
    for (int cc = 0; cc < 16; ++cc)
      s += part[((size_t)bh * 16 + cc) * 2048 + idx];
    ctx[(size_t)bh * 2048 + idx] = s;
  }
  if (tid < 64) {
    float s = 0.f;
#pragma unroll
    for (int cc = 0; cc < 16; ++cc) s += partk[((size_t)bh * 16 + cc) * 64 + tid];
    ksum[bh * 64 + tid] = s;
  }
}

// ===== btprep: pack [ctx | ksum | 0] into B-operand hi/lo bf16: Bt[bh][48][BTS] =====
__global__ __launch_bounds__(256) void btprep_kernel(
    const float* __restrict__ ctx, const float* __restrict__ ksum,
    u16* __restrict__ Bt) {
  int bh = blockIdx.x, tid = threadIdx.x;
  for (int idx = tid; idx < 48 * 64; idx += 256) {
    int n = idx >> 6, k = idx & 63;
    float v = 0.f;
    if (n < 32) v = ctx[(size_t)bh * 2048 + k * 32 + n];
    else if (n == 32) v = ksum[bh * 64 + k];
    u16 hi = f2bf(v);
    u16 lo = f2bf(v - bf2f(hi));
    u16* row = Bt + ((size_t)bh * 48 + n) * BTS;
    row[k] = hi;
    row[64 + k] = lo;
  }
}

// ===== attnout via MFMA: ao = (qp@ctx)/(qp@ksum) =====
__global__ __launch_bounds__(256) void attnout_kernel(
    const u16* __restrict__ qp, const u16* __restrict__ Bt,
    u16* __restrict__ ao, int hf) {
  __shared__ __align__(16) u16 BtS[48 * BTS];
  int tid = threadIdx.x;
  int rb = blockIdx.x, head = blockIdx.y;
  int t0l = rb * 128;
  int bhg = ((hf * 32768 + t0l) >> 13) * 8 + head;
  {
    const uint4* src = (const uint4*)(Bt + (size_t)bhg * 48 * BTS);
    for (int i = tid; i < 48 * BTS / 8; i += 256) ((uint4*)BtS)[i] = src[i];
  }
  __syncthreads();
  int w = tid >> 6, lane = tid & 63;
  int lr = lane & 15, lq = lane >> 4;
  int tw = t0l + w * 32;
  const u16* qpb = qp + (size_t)(hf * 32768 + tw) * 512 + head * 64;
  bf16x8 af[2][2];
#pragma unroll
  for (int mt = 0; mt < 2; ++mt)
#pragma unroll
    for (int kc = 0; kc < 2; ++kc)
      af[mt][kc] = *(const bf16x8*)(qpb + (size_t)(mt * 16 + lr) * 512 + kc * 32 + lq * 8);
  f32x4 c0[2], c1[2], c2[2];
#pragma unroll
  for (int mt = 0; mt < 2; ++mt) {
    c0[mt] = (f32x4){0.f, 0.f, 0.f, 0.f};
    c1[mt] = (f32x4){0.f, 0.f, 0.f, 0.f};
    c2[mt] = (f32x4){0.f, 0.f, 0.f, 0.f};
  }
#pragma unroll
  for (int kc = 0; kc < 4; ++kc) {
    bf16x8 b0 = *(const bf16x8*)(BtS + (size_t)(0 * 16 + lr) * BTS + kc * 32 + lq * 8);
    bf16x8 b1 = *(const bf16x8*)(BtS + (size_t)(1 * 16 + lr) * BTS + kc * 32 + lq * 8);
    bf16x8 b2 = *(const bf16x8*)(BtS + (size_t)(2 * 16 + lr) * BTS + kc * 32 + lq * 8);
#pragma unroll
    for (int mt = 0; mt < 2; ++mt) {
      bf16x8 a = af[mt][kc & 1];
      c0[mt] = __builtin_amdgcn_mfma_f32_16x16x32_bf16(a, b0, c0[mt], 0, 0, 0);
      c1[mt] = __builtin_amdgcn_mfma_f32_16x16x32_bf16(a, b1, c1[mt], 0, 0, 0);
      c2[mt] = __builtin_amdgcn_mfma_f32_16x16x32_bf16(a, b2, c2[mt], 0, 0, 0);
    }
  }
#pragma unroll
  for (int mt = 0; mt < 2; ++mt)
#pragma unroll
    for (int r = 0; r < 4; ++r) {
      float den = __shfl(c2[mt][r], lane & 48);
      int rowl = tw + mt * 16 + lq * 4 + r;
      float inv = 1.f / den;
      ao[(size_t)rowl * 256 + head * 32 + lr] = f2bf(c0[mt][r] * inv);
      ao[(size_t)rowl * 256 + head * 32 + 16 + lr] = f2bf(c1[mt][r] * inv);
    }
}

// ================= mean pool + final FC (fp32 h) =================
__global__ __launch_bounds__(256) void pool_kernel(
    const float* __restrict__ h, float* __restrict__ pooled) {
  int b = blockIdx.x, chunk = blockIdx.y, j = threadIdx.x;
  const float* hp = h + (size_t)(b * D_S + chunk * 256) * 256 + j;
  float acc = 0.f;
#pragma unroll 4
  for (int s = 0; s < 256; ++s) acc += hp[(size_t)s * 256];
  atomicAdd(pooled + b * 256 + j, acc);
}

__global__ __launch_bounds__(64) void final_kernel(
    const float* __restrict__ pooled, const float* __restrict__ fcw,
    const float* __restrict__ fcb, float* __restrict__ out) {
  int tid = threadIdx.x;
  if (tid >= 16) return;
  int b = tid >> 1, c = tid & 1;
  float acc = 0.f;
  for (int j = 0; j < 256; ++j) acc += pooled[b * 256 + j] * fcw[j * 2 + c];
  out[b * 2 + c] = acc * (1.f / 8192.f) + fcb[c];
}

extern "C" void kernel_launch(void* const* d_in, const int* in_sizes, int n_in,
                              void* d_out, int out_size, void* d_ws, size_t ws_size,
                              hipStream_t stream) {
  const float* x     = (const float*)d_in[0];
  const float* emb_w = (const float*)d_in[1];
  const float* emb_b = (const float*)d_in[2];
  const float* pos   = (const float*)d_in[3];
  const float* ln1_g = (const float*)d_in[4];
  const float* ln1_b = (const float*)d_in[5];
  const float* wq    = (const float*)d_in[6];
  const float* wk    = (const float*)d_in[7];
  const float* wv    = (const float*)d_in[8];
  const float* wo    = (const float*)d_in[9];
  const float* bo    = (const float*)d_in[10];
  const float* ln2_g = (const float*)d_in[11];
  const float* ln2_b = (const float*)d_in[12];
  const float* w1    = (const float*)d_in[13];
  const float* b1    = (const float*)d_in[14];
  const float* w2    = (const float*)d_in[15];
  const float* b2    = (const float*)d_in[16];
  const float* proj  = (const float*)d_in[17];
  const float* fc_w  = (const float*)d_in[18];
  const float* fc_b  = (const float*)d_in[19];

  if (ws_size < NEED_BYTES) {
    report_kernel<<<1, 64, 0, stream>>>((float*)d_out, (float)ws_size);
    return;
  }

  float* ws = (float*)d_ws;
  float* h      = ws + OFF_H;
  u16* xnb      = (u16*)(ws + OFF_XNB);
  u16* BIG      = (u16*)(ws + OFF_BIG);
  u16* Vb       = (u16*)(ws + OFF_V);
  u16* WKPt     = (u16*)(ws + OFF_WKP);
  u16* WQPt     = (u16*)(ws + OFF_WQP);
  u16* WKt      = (u16*)(ws + OFF_WK);
  u16* WQt      = (u16*)(ws + OFF_WQ);
  u16* WVt      = (u16*)(ws + OFF_WV);
  u16* WOt      = (u16*)(ws + OFF_WO);
  u16* W1t      = (u16*)(ws + OFF_W1);
  u16* W2t      = (u16*)(ws + OFF_W2);
  u16* dg       = (u16*)(ws + OFF_DG);
  unsigned int* kmaxk = (unsigned int*)(ws + OFF_KMAX);
  float* part   = ws + OFF_PART;
  u16* Bt       = (u16*)(ws + OFF_PART);  // reuses part after ctxreduce (btprep reads ctx/ksum only)
  float* partk  = ws + OFF_PARTK;
  float* ctx    = ws + OFF_CTX;
  float* ksum   = ws + OFF_KSUM;
  float* pooled = ws + OFF_POOL;

  // ---- embed as MFMA GEMM ----
  xcvt_kernel<<<4096, 256, 0, stream>>>(x, BIG);
  wsplit_kernel<<<64, 256, 0, stream>>>(emb_w, WKPt, 64, 256, 8);
  mfma_gemm<4, 0, 0, 0, 2><<<dim3(512, 2), 256, 0, stream>>>(
      BIG, WKPt, nullptr, emb_b, pos, nullptr, h, nullptr, nullptr, nullptr, 256, 64);

  for (int l = 0; l < D_L; ++l) {
    const float* pj = proj + l * 2048;
    ln_kernel<<<TOK / 4, 256, 0, stream>>>(h, xnb, ln1_g + l * 256, ln1_b + l * 256);
    wprep_kernel<<<4096, 256, 0, stream>>>(
        wk + l * 65536, wq + l * 65536, wv + l * 65536, wo + l * 65536,
        w1 + l * 262144, w2 + l * 262144, pj,
        WKPt, WQPt, WKt, WQt, WVt, WOt, W1t, W2t, kmaxk);

    // fused xp(+kmax) and diag(k|q): one launch, y<4 xp / y>=4 diag
    mfma_gemm<6, 0, 0, 1, 1><<<dim3(512, 8), 256, 0, stream>>>(
        xnb, WKPt, WKt, nullptr, nullptr, nullptr, nullptr, BIG, dg, kmaxk, 512, 256);
    // context accumulation per half (exp fused into staging)
    for (int hf = 0; hf < 2; ++hf) {
      const u16* xh = xnb + (size_t)hf * 32768 * 256;
      mfma_gemm<0, 0, 0, 1, 2><<<dim3(256, 2), 256, 0, stream>>>(
          xh, WVt, nullptr, nullptr, nullptr, nullptr, nullptr, Vb, nullptr, nullptr, 256, 256);
      ctxaccum_kernel<<<dim3(32, 16), 256, 0, stream>>>(BIG, Vb, dg, kmaxk, part, partk, hf);
    }
    ctxreduce_kernel<<<64, 256, 0, stream>>>(part, partk, ctx, ksum);
    btprep_kernel<<<64, 256, 0, stream>>>(ctx, ksum, Bt);
    // qp (overwrites BIG; xp dead), single-plane WQP
    mfma_gemm<3, 0, 0, 1, 1><<<dim3(512, 4), 256, 0, stream>>>(
        xnb, WQPt, nullptr, nullptr, nullptr, dg, nullptr, BIG, nullptr, nullptr, 512, 256);
    for (int hf = 0; hf < 2; ++hf) {
      float* hh = h + (size_t)hf * 32768 * 256;
      attnout_kernel<<<dim3(256, 8), 256, 0, stream>>>(BIG, Bt, Vb, hf);
      mfma_gemm<0, 0, 1, 0, 2><<<dim3(256, 2), 256, 0, stream>>>(
          Vb, WOt, nullptr, bo + l * 256, nullptr, nullptr, hh, nullptr, nullptr, nullptr, 256, 256);
    }

    ln_kernel<<<TOK / 4, 256, 0, stream>>>(h, xnb, ln2_g + l * 256, ln2_b + l * 256);
    for (int hf = 0; hf < 2; ++hf) {
      const u16* xh = xnb + (size_t)hf * 32768 * 256;
      float* hh = h + (size_t)hf * 32768 * 256;
      // FFN single-plane bf16 this round (KM=1)
      mfma_gemm<0, 1, 0, 1, 1><<<dim3(256, 8), 256, 0, stream>>>(
          xh, W1t, nullptr, b1 + l * 1024, nullptr, nullptr, nullptr, BIG, nullptr, nullptr, 1024, 256);
      mfma_gemm<0, 0, 1, 0, 1><<<dim3(256, 2), 256, 0, stream>>>(
          BIG, W2t, nullptr, b2 + l * 256, nullptr, nullptr, hh, nullptr, nullptr, nullptr, 256, 1024);
    }
  }

  zero_kernel<<<8, 256, 0, stream>>>(pooled, 2048);
  pool_kernel<<<dim3(8, 32), 256, 0, stream>>>(h, pooled);
  final_kernel<<<1, 64, 0, stream>>>(pooled, fc_w, fc_b, (float*)d_out);
}